// Round 8
// baseline (509.510 us; speedup 1.0000x reference)
//
#include <hip/hip_runtime.h>

typedef __attribute__((ext_vector_type(8))) short bf16x8;
typedef __attribute__((ext_vector_type(8))) unsigned short ushort8;
typedef __attribute__((ext_vector_type(4))) unsigned short ushortx4;
typedef __attribute__((ext_vector_type(4))) float f32x4;

#define BM 256
#define BN 256
#define BK 64

// ---------- helpers ----------
__device__ __forceinline__ unsigned short f2bf(float f) {
  union { float f; unsigned u; } c; c.f = f;
  return (unsigned short)((c.u + 0x7fffu + ((c.u >> 16) & 1u)) >> 16);  // RNE
}
__device__ __forceinline__ float bf2f(unsigned short u) {
  union { unsigned u; float f; } c; c.u = ((unsigned)u) << 16;
  return c.f;
}
__device__ __forceinline__ float fast_tanh(float x) {
  float e = __expf(2.f * x);                       // inf for large x -> rcp->0 -> 1
  return 1.f - 2.f * __builtin_amdgcn_rcpf(e + 1.f);
}
__device__ __forceinline__ float fast_sigmoid(float x) {
  return __builtin_amdgcn_rcpf(1.f + __expf(-x));
}
__device__ __forceinline__ void gload16(const void* g, void* lds) {
  __builtin_amdgcn_global_load_lds(
      (const __attribute__((address_space(1))) unsigned int*)g,
      (__attribute__((address_space(3))) unsigned int*)lds, 16, 0, 0);
}
__device__ __forceinline__ void bar() {
  asm volatile("" ::: "memory");
  __builtin_amdgcn_s_barrier();
  asm volatile("" ::: "memory");
}
// rule #18: explicit lgkmcnt wait + sched_barrier so MFMA can't hoist above it
__device__ __forceinline__ void lgkm0_fence() {
  asm volatile("s_waitcnt lgkmcnt(0)" ::: "memory");
  __builtin_amdgcn_sched_barrier(0);
}
template <int N> __device__ __forceinline__ void vwait() {
  if constexpr (N < 0) {
  } else if constexpr (N == 2) asm volatile("s_waitcnt vmcnt(2)" ::: "memory");
  else if constexpr (N == 0) asm volatile("s_waitcnt vmcnt(0)" ::: "memory");
}

// 16-MFMA pure cluster: acc[ro+i][n] += a[i] x b[n]
__device__ __forceinline__ void mfma16(const bf16x8 (&a)[4], const bf16x8 (&b)[4], int ro,
                                       f32x4 (&acc)[8][4]) {
  __builtin_amdgcn_s_setprio(1);
#pragma unroll
  for (int i = 0; i < 4; ++i)
#pragma unroll
    for (int n = 0; n < 4; ++n)
      acc[ro + i][n] =
          __builtin_amdgcn_mfma_f32_16x16x32_bf16(a[i], b[n], acc[ro + i][n], 0, 0, 0);
  __builtin_amdgcn_s_setprio(0);
}

// K-tile = 4 phases over (kk, qm): ph1 (kk0,qm0): 4A+4B reads; ph2 (kk0,qm1): 4A;
// ph3 (kk1,qm0): 4A+4B; ph4 (kk1,qm1): 4A  -> balanced 8/4/8/4 ds_read_b128/wave.
// Each phase: {reads; stage; [vwait]} BAR {lgkm0+sched_bar; 16 MFMA} BAR.
// Stages: all 4 half-tiles of t+1 go to the NEXT buffer (cur fully live to ph4):
//   ph1: SB1(t+1)  ph2: SA0(t+1)  ph3: SB0(t+1)  ph4: SA1(t+1)
// Waits (ledger, steady state; 2 loads per stage, FIFO vmcnt):
//   W1=vmcnt(2) in ph1 (after SB1 issue): retires SA1(t-1) = A(t)h1 before ph2.
//   W4=vmcnt(2) in ph4 (after SA1 issue): retires SB1/SA0/SB0(t+1) before t+1.ph1.
// LDS bytes: row stride 128; A half (qm) = +16384; B: (n>>1)*16384 + (n&1)*2048.
template <bool ST, int W1, int W4>
__device__ __forceinline__ void ktile(
    const char* rAk0, const char* rAk1,     // cur A read bases (kk slot 0/1)
    const char* rBk0, const char* rBk1,     // cur B read bases
    char* dNA, char* dNB,                   // NEXT-buffer stage dest (buf + t*16)
    const unsigned short* pA0, const unsigned short* pA1,
    const unsigned short* pB0, const unsigned short* pB1,
    int kN, f32x4 (&acc)[8][4]) {
  bf16x8 a[4], a2[4], b[4];
  // ---- ph1: kk0,qm0
#pragma unroll
  for (int i = 0; i < 4; ++i) a[i] = *(const bf16x8*)(rAk0 + i * 2048);
#pragma unroll
  for (int n = 0; n < 4; ++n)
    b[n] = *(const bf16x8*)(rBk0 + (n >> 1) * 16384 + (n & 1) * 2048);
  if (ST) {
    gload16(pB0 + 32768 + kN, dNB + 16384);
    gload16(pB1 + 32768 + kN, dNB + 16384 + 8192);
  }
  vwait<W1>();
  bar();
  lgkm0_fence();
  mfma16(a, b, 0, acc);
  bar();
  // ---- ph2: kk0,qm1
#pragma unroll
  for (int i = 0; i < 4; ++i) a2[i] = *(const bf16x8*)(rAk0 + 16384 + i * 2048);
  if (ST) {
    gload16(pA0 + kN, dNA);
    gload16(pA1 + kN, dNA + 8192);
  }
  bar();
  lgkm0_fence();
  mfma16(a2, b, 4, acc);
  bar();
  // ---- ph3: kk1,qm0
#pragma unroll
  for (int i = 0; i < 4; ++i) a[i] = *(const bf16x8*)(rAk1 + i * 2048);
#pragma unroll
  for (int n = 0; n < 4; ++n)
    b[n] = *(const bf16x8*)(rBk1 + (n >> 1) * 16384 + (n & 1) * 2048);
  if (ST) {
    gload16(pB0 + kN, dNB);
    gload16(pB1 + kN, dNB + 8192);
  }
  bar();
  lgkm0_fence();
  mfma16(a, b, 0, acc);
  bar();
  // ---- ph4: kk1,qm1
#pragma unroll
  for (int i = 0; i < 4; ++i) a2[i] = *(const bf16x8*)(rAk1 + 16384 + i * 2048);
  if (ST) {
    gload16(pA0 + 65536 + kN, dNA + 16384);
    gload16(pA1 + 65536 + kN, dNA + 16384 + 8192);
  }
  vwait<W4>();
  bar();
  lgkm0_fence();
  mfma16(a2, b, 4, acc);
  bar();
}

// Shared setup + pipeline. LDS layout (verified r3-r7):
// A: la = qm*128 + wr*64 + i*16 + (lane&15) holds tile row wr*128+qm*64+i*16+(lane&15)
// B: lb = qn*128 + wc*32 + j*16 + (lane&15); byte(l,s) = l*128 + (s^(l&7))*16.
// Staged linear-dest with inverse-swizzled global source.
#define GEMM_SETUP_AND_PIPELINE(Ag, Bg)                                                    \
  int t = threadIdx.x, lane = t & 63, wave = t >> 6;                                       \
  int wr = wave >> 2, wc = wave & 3;                                                       \
  int sl0 = ((lane >> 4) ^ (lane & 7)) * 16;                                               \
  int sl1 = (((lane >> 4) + 4) ^ (lane & 7)) * 16;                                         \
  int aLane = (wr * 64 + (lane & 15)) * 128;                                               \
  int bLane = (wc * 32 + (lane & 15)) * 128;                                               \
  const char* rA0k0 = (const char*)As0 + aLane + sl0;                                      \
  const char* rA0k1 = (const char*)As0 + aLane + sl1;                                      \
  const char* rA1k0 = (const char*)As1 + aLane + sl0;                                      \
  const char* rA1k1 = (const char*)As1 + aLane + sl1;                                      \
  const char* rB0k0 = (const char*)Bs0 + bLane + sl0;                                      \
  const char* rB0k1 = (const char*)Bs0 + bLane + sl1;                                      \
  const char* rB1k0 = (const char*)Bs1 + bLane + sl0;                                      \
  const char* rB1k1 = (const char*)Bs1 + bLane + sl1;                                      \
  char* dA0 = (char*)As0 + t * 16;                                                         \
  char* dA1 = (char*)As1 + t * 16;                                                         \
  char* dB0 = (char*)Bs0 + t * 16;                                                         \
  char* dB1 = (char*)Bs1 + t * 16;                                                         \
  int l3 = t >> 3;                                                                         \
  int sgE = ((t & 7) ^ (l3 & 7)) * 8;                                                      \
  const unsigned short* pA0 = Ag + (size_t)(m0 + l3) * 1024 + sgE;                         \
  const unsigned short* pA1 = pA0 + (size_t)128 * 1024;                                    \
  int nB0 = ((l3 >> 5) << 6) + (l3 & 31);                                                  \
  const unsigned short* pB0 = Bg + (size_t)(n0 + nB0) * 1024 + sgE;                        \
  const unsigned short* pB1 = pB0 + (size_t)128 * 1024;                                    \
  f32x4 acc[8][4] = {};                                                                    \
  /* prologue tile 0: SA0, SB0, SB1, SA1 (issue order matters for the ledger) */           \
  gload16(pA0, dA0); gload16(pA1, dA0 + 8192);                                             \
  gload16(pB0, dB0); gload16(pB1, dB0 + 8192);                                             \
  gload16(pB0 + 32768, dB0 + 16384); gload16(pB1 + 32768, dB0 + 16384 + 8192);             \
  gload16(pA0 + 65536, dA0 + 16384); gload16(pA1 + 65536, dA0 + 16384 + 8192);             \
  vwait<2>();                                                                              \
  bar();                                                                                   \
  _Pragma("unroll 1") for (int kt = 0; kt < 14; kt += 2) {                                 \
    ktile<true, 2, 2>(rA0k0, rA0k1, rB0k0, rB0k1, dA1, dB1, pA0, pA1, pB0, pB1,            \
                      (kt + 1) * 64, acc);                                                 \
    ktile<true, 2, 2>(rA1k0, rA1k1, rB1k0, rB1k1, dA0, dB0, pA0, pA1, pB0, pB1,            \
                      (kt + 2) * 64, acc);                                                 \
  }                                                                                        \
  ktile<true, 2, 2>(rA0k0, rA0k1, rB0k0, rB0k1, dA1, dB1, pA0, pA1, pB0, pB1, 960, acc);   \
  ktile<false, 0, -1>(rA1k0, rA1k1, rB1k0, rB1k1, dA0, dB0, pA0, pA1, pB0, pB1, 0, acc);

__device__ __forceinline__ void tile_coords(int bid, int& m0, int& n0, int& nt) {
  // 1024 blocks, 8 XCDs, bijective; nt fastest within an XCD for A-panel L2 reuse
  int lin = (bid & 7) * 128 + (bid >> 3);
  int mt = lin >> 2;
  nt = lin & 3;
  m0 = mt * BM;
  n0 = nt * BN;
}

// ---------- prep: convert (2048 blocks) + transpose (512) + query partials (32) ----------
__global__ __launch_bounds__(256) void prep_kernel(
    const float* __restrict__ seq, unsigned short* __restrict__ seqb,
    const float* __restrict__ Wk, const float* __restrict__ Wg,
    unsigned short* __restrict__ WkT, unsigned short* __restrict__ WgT,
    const float* __restrict__ q, const float* __restrict__ Wq,
    float* __restrict__ qp) {
  __shared__ float smem[4160];
  int bid = blockIdx.x, t = threadIdx.x;
  if (bid < 2048) {
    size_t i = ((size_t)bid * 256 + t) * 8;
    const size_t stride = (size_t)2048 * 256 * 8;
    for (; i < (size_t)67108864; i += stride) {
      f32x4 v0 = *(const f32x4*)(seq + i);
      f32x4 v1 = *(const f32x4*)(seq + i + 4);
      ushort8 o;
#pragma unroll
      for (int k = 0; k < 4; ++k) { o[k] = f2bf(v0[k]); o[k + 4] = f2bf(v1[k]); }
      *(ushort8*)(seqb + i) = o;
    }
  } else if (bid < 2560) {
    int b2 = bid - 2048;
    int mat = b2 >> 8;
    int tid = b2 & 255;
    int tr = tid >> 4, tc = tid & 15;
    const float* src = mat ? Wg : Wk;
    unsigned short* dst = mat ? WgT : WkT;
    int r0 = tr * 64, c0 = tc * 64;
    int lr = t >> 6, lc = t & 63;
#pragma unroll
    for (int i = 0; i < 16; ++i) {
      int r = i * 4 + lr;
      smem[r * 65 + lc] = src[(size_t)(r0 + r) * 1024 + c0 + lc];
    }
    __syncthreads();
#pragma unroll
    for (int i = 0; i < 16; ++i) {
      int r = i * 4 + lr;
      dst[(size_t)(c0 + r) * 1024 + r0 + lc] = f2bf(smem[lc * 65 + r]);
    }
  } else {
    // query partials: qp[hc][b][a] = sum_{h in chunk} q[b][h]*Wq[h][a]
    int b3 = bid - 2560;           // 32 blocks
    int ac = b3 & 3, hc = b3 >> 2; // 4 a-chunks x 8 h-chunks
    int h0 = hc * 128;
    for (int i = t; i < 4096; i += 256) {
      int b = i >> 7, hh = i & 127;
      smem[b * 128 + hh] = q[(size_t)b * 1024 + h0 + hh];
    }
    __syncthreads();
    int a = ac * 256 + t;
    float acc[32] = {};
    for (int hh = 0; hh < 128; hh += 4) {
      float w0 = Wq[(size_t)(h0 + hh) * 1024 + a];
      float w1 = Wq[(size_t)(h0 + hh + 1) * 1024 + a];
      float w2 = Wq[(size_t)(h0 + hh + 2) * 1024 + a];
      float w3 = Wq[(size_t)(h0 + hh + 3) * 1024 + a];
#pragma unroll
      for (int b = 0; b < 32; ++b) {
        f32x4 qv = *(const f32x4*)&smem[b * 128 + hh];
        acc[b] += qv[0] * w0 + qv[1] * w1 + qv[2] * w2 + qv[3] * w3;
      }
    }
#pragma unroll
    for (int b = 0; b < 32; ++b) qp[((size_t)(hc * 32 + b)) * 1024 + a] = acc[b];
  }
}

// ---------- GEMM1: align = tanh(seqb@WkT^T + query) -> bf16 ----------
__global__ __launch_bounds__(512, 2) void gemm1_kernel(
    const unsigned short* __restrict__ seqb, const unsigned short* __restrict__ WkT,
    const float* __restrict__ qp, const float* __restrict__ bq,
    const float* __restrict__ bk, unsigned short* __restrict__ alignb) {
  __shared__ unsigned short As0[BM * BK], Bs0[BN * BK], As1[BM * BK], Bs1[BN * BK];
  int m0, n0, nt;
  tile_coords(blockIdx.x, m0, n0, nt);
  GEMM_SETUP_AND_PIPELINE(seqb, WkT)

  // epilogue: fold query reduce (8 partials + bq + bk), tanh, store bf16
  int bidx = m0 >> 11;  // 256-row tile stays in one batch (2048 % 256 == 0)
  float qv[4];
#pragma unroll
  for (int ni = 0; ni < 4; ++ni) {
    int col = n0 + wc * 64 + ni * 16 + (lane & 15);
    float s = bq[col] + bk[col];
#pragma unroll
    for (int hc = 0; hc < 8; ++hc) s += qp[((size_t)(hc * 32 + bidx)) * 1024 + col];
    qv[ni] = s;
  }
#pragma unroll
  for (int mi = 0; mi < 8; ++mi) {
    int row0 = m0 + wr * 128 + mi * 16 + ((lane >> 4) * 4);
#pragma unroll
    for (int ni = 0; ni < 4; ++ni) {
      int col = n0 + wc * 64 + ni * 16 + (lane & 15);
#pragma unroll
      for (int j = 0; j < 4; ++j) {
        float v = fast_tanh(acc[mi][ni][j] + qv[ni]);
        alignb[(size_t)(row0 + j) * 1024 + col] = f2bf(v);
      }
    }
  }
}

// ---------- GEMM2: scores_part[nt,row] = sum_col align*sigmoid(align@Wg+bg)*Ws ----------
__global__ __launch_bounds__(512, 2) void gemm2_kernel(
    const unsigned short* __restrict__ alignb, const unsigned short* __restrict__ WgT,
    const float* __restrict__ bg, const float* __restrict__ Ws,
    float* __restrict__ scores_part) {
  __shared__ unsigned short As0[BM * BK], Bs0[BN * BK], As1[BM * BK], Bs1[BN * BK];
  __shared__ float sred[BM * 4];
  int m0, n0, nt;
  tile_coords(blockIdx.x, m0, n0, nt);
  GEMM_SETUP_AND_PIPELINE(alignb, WgT)

#pragma unroll
  for (int mi = 0; mi < 8; ++mi) {
#pragma unroll
    for (int j = 0; j < 4; ++j) {
      int rloc = wr * 128 + mi * 16 + ((lane >> 4) * 4) + j;
      int row = m0 + rloc;
      float p = 0.f;
#pragma unroll
      for (int ni = 0; ni < 4; ++ni) {
        int col = n0 + wc * 64 + ni * 16 + (lane & 15);
        float gate = fast_sigmoid(acc[mi][ni][j] + bg[col]);
        float al = bf2f(alignb[(size_t)row * 1024 + col]);
        p += al * gate * Ws[col];
      }
      p += __shfl_xor(p, 1);
      p += __shfl_xor(p, 2);
      p += __shfl_xor(p, 4);
      p += __shfl_xor(p, 8);
      if ((lane & 15) == 0) sred[rloc * 4 + wc] = p;
    }
  }
  __syncthreads();
  if (t < 256)
    scores_part[(size_t)nt * 65536 + m0 + t] =
        sred[t * 4] + sred[t * 4 + 1] + sred[t * 4 + 2] + sred[t * 4 + 3];
}

// ---------- softmax over S=2048 per batch; writes weights output ----------
__global__ __launch_bounds__(256) void softmax_kernel(const float* __restrict__ sp,
                                                      float* __restrict__ wout) {
  __shared__ float red[256];
  int b = blockIdx.x, t = threadIdx.x;
  float sc[8];
  float lmax = -1e30f;
#pragma unroll
  for (int i = 0; i < 8; ++i) {
    int s = i * 256 + t;
    float v = 0.f;
#pragma unroll
    for (int n = 0; n < 4; ++n) v += sp[(size_t)n * 65536 + b * 2048 + s];
    sc[i] = v;
    lmax = fmaxf(lmax, v);
  }
  red[t] = lmax;
  __syncthreads();
  for (int off = 128; off > 0; off >>= 1) {
    if (t < off) red[t] = fmaxf(red[t], red[t + off]);
    __syncthreads();
  }
  float mx = red[0];
  __syncthreads();
  float lsum = 0.f;
#pragma unroll
  for (int i = 0; i < 8; ++i) {
    sc[i] = expf(sc[i] - mx);
    lsum += sc[i];
  }
  red[t] = lsum;
  __syncthreads();
  for (int off = 128; off > 0; off >>= 1) {
    if (t < off) red[t] += red[t + off];
    __syncthreads();
  }
  float inv = 1.f / red[0];
#pragma unroll
  for (int i = 0; i < 8; ++i) wout[(size_t)b * 2048 + i * 256 + t] = sc[i] * inv;
}

// ---------- context partials (bf16 seq read, 4 h per thread, 16 s-chunks) ----------
__global__ __launch_bounds__(256) void context_kernel(const unsigned short* __restrict__ seqb,
                                                      const float* __restrict__ wts,
                                                      float* __restrict__ ctx_part) {
  __shared__ float wsh[128];
  int b = blockIdx.x, t = threadIdx.x, s0 = blockIdx.z * 128;
  int h0 = t * 4;
  if (t < 128) wsh[t] = wts[(size_t)b * 2048 + s0 + t];
  __syncthreads();
  float a0 = 0.f, a1 = 0.f, a2 = 0.f, a3 = 0.f;
  const unsigned short* p = seqb + ((size_t)b * 2048 + s0) * 1024 + h0;
#pragma unroll 4
  for (int s = 0; s < 128; ++s) {
    ushortx4 v = *(const ushortx4*)(p + (size_t)s * 1024);
    float w = wsh[s];
    a0 += w * bf2f(v[0]);
    a1 += w * bf2f(v[1]);
    a2 += w * bf2f(v[2]);
    a3 += w * bf2f(v[3]);
  }
  float* dst = ctx_part + (size_t)(blockIdx.z * 32 + b) * 1024 + h0;
  dst[0] = a0; dst[1] = a1; dst[2] = a2; dst[3] = a3;
}

// ---------- pre partials: Wo read ONCE. grid (16 k-chunks of 128, 4 h-chunks) ----------
__global__ __launch_bounds__(256) void pre_kernel(const float* __restrict__ ctx_part,
                                                  const float* __restrict__ q,
                                                  const float* __restrict__ Wo,
                                                  float* __restrict__ pre_part) {
  __shared__ float fin[32 * 128];
  int kc = blockIdx.x, hc = blockIdx.y, t = threadIdx.x;
  int k0 = kc * 128, h0 = hc * 256;
  for (int i = t; i < 4096; i += 256) {
    int b = i >> 7, kk = i & 127, k = k0 + kk;
    float f;
    if (k < 1024) {
      f = 0.f;
#pragma unroll
      for (int s = 0; s < 16; ++s) f += ctx_part[((size_t)(s * 32 + b)) * 1024 + k];
    } else {
      f = q[(size_t)b * 1024 + (k - 1024)];
    }
    fin[b * 128 + kk] = f;
  }
  __syncthreads();
  int h = h0 + t;
  float acc[32] = {};
  for (int kk = 0; kk < 128; kk += 4) {
    float w0 = Wo[(size_t)(k0 + kk) * 1024 + h];
    float w1 = Wo[(size_t)(k0 + kk + 1) * 1024 + h];
    float w2 = Wo[(size_t)(k0 + kk + 2) * 1024 + h];
    float w3 = Wo[(size_t)(k0 + kk + 3) * 1024 + h];
#pragma unroll
    for (int b = 0; b < 32; ++b) {
      f32x4 fv = *(const f32x4*)&fin[b * 128 + kk];
      acc[b] += fv[0] * w0 + fv[1] * w1 + fv[2] * w2 + fv[3] * w3;
    }
  }
#pragma unroll
  for (int b = 0; b < 32; ++b) pre_part[((size_t)(kc * 32 + b)) * 1024 + h] = acc[b];
}

// ---------- final: residual + layernorm ----------
__global__ __launch_bounds__(256) void ln_kernel(const float* __restrict__ pre_part,
                                                 const float* __restrict__ q,
                                                 const float* __restrict__ bo,
                                                 const float* __restrict__ gamma,
                                                 const float* __restrict__ beta,
                                                 float* __restrict__ outF) {
  __shared__ float red[256];
  int b = blockIdx.x, t = threadIdx.x;
  float v[4];
  float lsum = 0.f;
#pragma unroll
  for (int i = 0; i < 4; ++i) {
    int h = i * 256 + t;
    float x = bo[h] + q[(size_t)b * 1024 + h];
#pragma unroll
    for (int kc = 0; kc < 16; ++kc) x += pre_part[((size_t)(kc * 32 + b)) * 1024 + h];
    v[i] = x;
    lsum += x;
  }
  red[t] = lsum;
  __syncthreads();
  for (int off = 128; off > 0; off >>= 1) {
    if (t < off) red[t] += red[t + off];
    __syncthreads();
  }
  float mu = red[0] * (1.f / 1024.f);
  __syncthreads();
  float lv = 0.f;
#pragma unroll
  for (int i = 0; i < 4; ++i) {
    float d = v[i] - mu;
    lv += d * d;
  }
  red[t] = lv;
  __syncthreads();
  for (int off = 128; off > 0; off >>= 1) {
    if (t < off) red[t] += red[t + off];
    __syncthreads();
  }
  float var = red[0] * (1.f / 1024.f);
  float rs = rsqrtf(var + 1e-5f);
#pragma unroll
  for (int i = 0; i < 4; ++i) {
    int h = i * 256 + t;
    outF[(size_t)b * 1024 + h] = (v[i] - mu) * rs * gamma[h] + beta[h];
  }
}

// ---------- host ----------
extern "C" void kernel_launch(void* const* d_in, const int* in_sizes, int n_in,
                              void* d_out, int out_size, void* d_ws, size_t ws_size,
                              hipStream_t stream) {
  const float* seq = (const float*)d_in[0];
  const float* q = (const float*)d_in[1];
  const float* Wk = (const float*)d_in[2];
  const float* bk = (const float*)d_in[3];
  const float* Wq = (const float*)d_in[4];
  const float* bq = (const float*)d_in[5];
  const float* Wg = (const float*)d_in[6];
  const float* bg = (const float*)d_in[7];
  const float* Ws = (const float*)d_in[8];
  // d_in[9] = bs: softmax is shift-invariant, cancels everywhere it appears
  const float* Wo = (const float*)d_in[10];
  const float* bo = (const float*)d_in[11];
  const float* gamma = (const float*)d_in[12];
  const float* beta = (const float*)d_in[13];

  float* outF = (float*)d_out;         // fused [32,1024]
  float* outW = outF + 32 * 1024;      // weights [32,2048]

  char* ws = (char*)d_ws;
  unsigned short* alignb = (unsigned short*)ws;  ws += (size_t)134217728;  // [65536,1024] bf16
  unsigned short* seqb = (unsigned short*)ws;    ws += (size_t)134217728;  // [65536,1024] bf16
  unsigned short* WkT = (unsigned short*)ws;     ws += 2097152;            // [1024,1024] bf16
  unsigned short* WgT = (unsigned short*)ws;     ws += 2097152;
  float* qp = (float*)ws;                        ws += 1048576;            // [8,32,1024]
  float* scores_part = (float*)ws;               ws += 1048576;            // [4,65536]
  float* ctx_part = (float*)ws;                  ws += 2097152;            // [16,32,1024]
  float* pre_part = (float*)ws;                  ws += 2097152;            // [16,32,1024]
  if (ws_size < (size_t)(ws - (char*)d_ws)) return;  // insufficient scratch

  prep_kernel<<<2592, 256, 0, stream>>>(seq, seqb, Wk, Wg, WkT, WgT, q, Wq, qp);
  gemm1_kernel<<<1024, 512, 0, stream>>>(seqb, WkT, qp, bq, bk, alignb);
  gemm2_kernel<<<1024, 512, 0, stream>>>(alignb, WgT, bg, Ws, scores_part);
  softmax_kernel<<<32, 256, 0, stream>>>(scores_part, outW);
  context_kernel<<<dim3(32, 1, 16), 256, 0, stream>>>(seqb, outW, ctx_part);
  pre_kernel<<<dim3(16, 4), 256, 0, stream>>>(ctx_part, q, Wo, pre_part);
  ln_kernel<<<32, 256, 0, stream>>>(pre_part, q, bo, gamma, beta, outF);
}

// Round 9
// 505.955 us; speedup vs baseline: 1.0070x; 1.0070x over previous
//
#include <hip/hip_runtime.h>

typedef __attribute__((ext_vector_type(8))) short bf16x8;
typedef __attribute__((ext_vector_type(8))) unsigned short ushort8;
typedef __attribute__((ext_vector_type(4))) unsigned short ushortx4;
typedef __attribute__((ext_vector_type(4))) float f32x4;

#define BM 256
#define BN 256
#define BK 64

// ---------- helpers ----------
__device__ __forceinline__ unsigned short f2bf(float f) {
  union { float f; unsigned u; } c; c.f = f;
  return (unsigned short)((c.u + 0x7fffu + ((c.u >> 16) & 1u)) >> 16);  // RNE
}
__device__ __forceinline__ float bf2f(unsigned short u) {
  union { unsigned u; float f; } c; c.u = ((unsigned)u) << 16;
  return c.f;
}
__device__ __forceinline__ float fast_tanh(float x) {
  float e = __expf(2.f * x);                       // inf for large x -> rcp->0 -> 1
  return 1.f - 2.f * __builtin_amdgcn_rcpf(e + 1.f);
}
__device__ __forceinline__ float fast_sigmoid(float x) {
  return __builtin_amdgcn_rcpf(1.f + __expf(-x));
}
__device__ __forceinline__ void gload16(const void* g, void* lds) {
  __builtin_amdgcn_global_load_lds(
      (const __attribute__((address_space(1))) unsigned int*)g,
      (__attribute__((address_space(3))) unsigned int*)lds, 16, 0, 0);
}
__device__ __forceinline__ void bar() {
  asm volatile("" ::: "memory");
  __builtin_amdgcn_s_barrier();
  asm volatile("" ::: "memory");
}
__device__ __forceinline__ void sb0() { __builtin_amdgcn_sched_barrier(0); }
template <int N> __device__ __forceinline__ void vlgkm() {
  if constexpr (N == 0) asm volatile("s_waitcnt lgkmcnt(0)" ::: "memory");
  else if constexpr (N == 4) asm volatile("s_waitcnt lgkmcnt(4)" ::: "memory");
  else if constexpr (N == 8) asm volatile("s_waitcnt lgkmcnt(8)" ::: "memory");
}
template <int N> __device__ __forceinline__ void vwait() {
  if constexpr (N < 0) {
  } else if constexpr (N == 2) asm volatile("s_waitcnt vmcnt(2)" ::: "memory");
  else if constexpr (N == 0) asm volatile("s_waitcnt vmcnt(0)" ::: "memory");
}

// 16-MFMA pure cluster: acc[ro+i][n] += a[i] x b[n]
__device__ __forceinline__ void mfma16(const bf16x8 (&a)[4], const bf16x8 (&b)[4], int ro,
                                       f32x4 (&acc)[8][4]) {
  __builtin_amdgcn_s_setprio(1);
#pragma unroll
  for (int i = 0; i < 4; ++i)
#pragma unroll
    for (int n = 0; n < 4; ++n)
      acc[ro + i][n] =
          __builtin_amdgcn_mfma_f32_16x16x32_bf16(a[i], b[n], acc[ro + i][n], 0, 0, 0);
  __builtin_amdgcn_s_setprio(0);
}

// K-tile = 4 phases over (kk,qm). SOFTWARE-PIPELINED ds_reads: phase p issues the
// reads for phase p+1, then waits counted lgkmcnt(N_just_issued) which retires the
// PREVIOUS phase's reads (feeding this phase's MFMA) while the new reads' LDS
// service overlaps this phase's MFMA. Fragment slots: aX=qm0, aY=qm1 (alternate),
// b0=kk0, b1=kk1 (each B set spans both row-halves, used by two phases).
//   ph1: MFMA(aX=A(kk0,qm0), b0) ; reads aY=A(kk0,qm1) [4]  ; stage SB0(t+1)
//   ph2: MFMA(aY, b0)            ; reads aX=A(kk1,qm0)+b1=B(kk1) [8]; stage SB1(t+1)
//   ph3: MFMA(aX, b1)            ; reads aY=A(kk1,qm1) [4]  ; stage SA1(t+1); vwait(2)
//   ph4: MFMA(aY, b1)            ; reads aX'=A'(kk0,qm0)+b0'=B'(kk0) from NEXT buf [8];
//                                  stage SA0(t+2) into CUR buf; vwait(2)
// vmcnt ledger (2 gloads/stage, FIFO; stage slots SA0@ph4(t-1),SB0@ph1,SB1@ph2,SA1@ph3):
//   end-ph3 vwait(2): retires SA0',SB0',SB1' (needed by ph4's reads), leaves SA1'.
//   end-ph4 vwait(2): retires SA1' (needed by ph1(t+1) reads), leaves SA0''.
// All stage->wait distances >= 2 phases (~1500cyc > 900cyc HBM latency).
// LDS WAR safety: stages issue AFTER the phase's BAR; the last ds_reads of any
// region were retired by a counted lgkm one phase earlier, and the BAR makes that
// collective across waves (desk-checked r8->r9).
template <bool ST, bool ST4, bool RD4, int W3, int W4>
__device__ __forceinline__ void ktile(
    const char* rAk0, const char* rAk1, const char* rBk1,   // cur-buf read bases
    const char* rAk0n, const char* rBk0n,                   // next-buf (ph4 reads)
    char* dAn, char* dBn,   // stage dests, tile t+1 (next buf), +t*16 applied
    char* dAc,              // stage dest SA0(t+2) (cur buf)
    const unsigned short* pA0, const unsigned short* pA1,
    const unsigned short* pB0, const unsigned short* pB1,
    int kN1, int kN2,
    bf16x8 (&aX)[4], bf16x8 (&aY)[4], bf16x8 (&b0)[4], bf16x8 (&b1)[4],
    f32x4 (&acc)[8][4]) {
  // ---- ph1
  bar();
#pragma unroll
  for (int i = 0; i < 4; ++i) aY[i] = *(const bf16x8*)(rAk0 + 16384 + i * 2048);
  if (ST) { gload16(pB0 + kN1, dBn); gload16(pB1 + kN1, dBn + 8192); }
  vlgkm<4>(); sb0();
  mfma16(aX, b0, 0, acc);
  // ---- ph2
  bar();
#pragma unroll
  for (int i = 0; i < 4; ++i) aX[i] = *(const bf16x8*)(rAk1 + i * 2048);
#pragma unroll
  for (int n = 0; n < 4; ++n)
    b1[n] = *(const bf16x8*)(rBk1 + (n >> 1) * 16384 + (n & 1) * 2048);
  if (ST) { gload16(pB0 + 32768 + kN1, dBn + 16384); gload16(pB1 + 32768 + kN1, dBn + 16384 + 8192); }
  vlgkm<8>(); sb0();
  mfma16(aY, b0, 4, acc);
  // ---- ph3
  bar();
#pragma unroll
  for (int i = 0; i < 4; ++i) aY[i] = *(const bf16x8*)(rAk1 + 16384 + i * 2048);
  if (ST) { gload16(pA0 + 65536 + kN1, dAn + 16384); gload16(pA1 + 65536 + kN1, dAn + 16384 + 8192); }
  vlgkm<4>(); sb0();
  mfma16(aX, b1, 0, acc);
  vwait<W3>();
  // ---- ph4
  bar();
  if (RD4) {
#pragma unroll
    for (int i = 0; i < 4; ++i) aX[i] = *(const bf16x8*)(rAk0n + i * 2048);
#pragma unroll
    for (int n = 0; n < 4; ++n)
      b0[n] = *(const bf16x8*)(rBk0n + (n >> 1) * 16384 + (n & 1) * 2048);
  }
  if (ST4) { gload16(pA0 + kN2, dAc); gload16(pA1 + kN2, dAc + 8192); }
  if (RD4) vlgkm<8>(); else vlgkm<0>();
  sb0();
  mfma16(aY, b1, 4, acc);
  vwait<W4>();
}

// Shared setup + pipeline. LDS layout (verified r3-r8):
// A: la = qm*128 + wr*64 + i*16 + (lane&15); B: lb = qn*128 + wc*32 + j*16 + (lane&15)
// byte(l,s) = l*128 + (s^(l&7))*16; staged linear-dest with inverse-swizzled source.
#define GEMM_SETUP_AND_PIPELINE(Ag, Bg)                                                    \
  int t = threadIdx.x, lane = t & 63, wave = t >> 6;                                       \
  int wr = wave >> 2, wc = wave & 3;                                                       \
  int sl0 = ((lane >> 4) ^ (lane & 7)) * 16;                                               \
  int sl1 = (((lane >> 4) + 4) ^ (lane & 7)) * 16;                                         \
  int aLane = (wr * 64 + (lane & 15)) * 128;                                               \
  int bLane = (wc * 32 + (lane & 15)) * 128;                                               \
  const char* rA0k0 = (const char*)As0 + aLane + sl0;                                      \
  const char* rA0k1 = (const char*)As0 + aLane + sl1;                                      \
  const char* rA1k0 = (const char*)As1 + aLane + sl0;                                      \
  const char* rA1k1 = (const char*)As1 + aLane + sl1;                                      \
  const char* rB0k0 = (const char*)Bs0 + bLane + sl0;                                      \
  const char* rB0k1 = (const char*)Bs0 + bLane + sl1;                                      \
  const char* rB1k0 = (const char*)Bs1 + bLane + sl0;                                      \
  const char* rB1k1 = (const char*)Bs1 + bLane + sl1;                                      \
  char* dA0 = (char*)As0 + t * 16;                                                         \
  char* dA1 = (char*)As1 + t * 16;                                                         \
  char* dB0 = (char*)Bs0 + t * 16;                                                         \
  char* dB1 = (char*)Bs1 + t * 16;                                                         \
  int l3 = t >> 3;                                                                         \
  int sgE = ((t & 7) ^ (l3 & 7)) * 8;                                                      \
  const unsigned short* pA0 = Ag + (size_t)(m0 + l3) * 1024 + sgE;                         \
  const unsigned short* pA1 = pA0 + (size_t)128 * 1024;                                    \
  int nB0 = ((l3 >> 5) << 6) + (l3 & 31);                                                  \
  const unsigned short* pB0 = Bg + (size_t)(n0 + nB0) * 1024 + sgE;                        \
  const unsigned short* pB1 = pB0 + (size_t)128 * 1024;                                    \
  f32x4 acc[8][4] = {};                                                                    \
  bf16x8 aX[4], aY[4], b0f[4], b1f[4];                                                     \
  /* prologue: stage tile0 halves SA0,SB0,SB1,SA1 */                                       \
  gload16(pA0, dA0); gload16(pA1, dA0 + 8192);                                             \
  gload16(pB0, dB0); gload16(pB1, dB0 + 8192);                                             \
  gload16(pB0 + 32768, dB0 + 16384); gload16(pB1 + 32768, dB0 + 16384 + 8192);             \
  gload16(pA0 + 65536, dA0 + 16384); gload16(pA1 + 65536, dA0 + 16384 + 8192);             \
  vwait<2>();                                                                              \
  bar();                                                                                   \
  /* ph0 (acts as ph4(-1)): read aX,b0 of tile0; stage SA0(1) */                           \
  _Pragma("unroll") for (int i = 0; i < 4; ++i)                                            \
      aX[i] = *(const bf16x8*)(rA0k0 + i * 2048);                                          \
  _Pragma("unroll") for (int n = 0; n < 4; ++n)                                            \
      b0f[n] = *(const bf16x8*)(rB0k0 + (n >> 1) * 16384 + (n & 1) * 2048);                \
  gload16(pA0 + 64, dA1); gload16(pA1 + 64, dA1 + 8192);                                   \
  vwait<2>();                                                                              \
  _Pragma("unroll 1") for (int kt = 0; kt < 14; kt += 2) {                                 \
    ktile<true, true, true, 2, 2>(rA0k0, rA0k1, rB0k1, rA1k0, rB1k0, dA1, dB1, dA0,        \
        pA0, pA1, pB0, pB1, (kt + 1) * 64, (kt + 2) * 64, aX, aY, b0f, b1f, acc);          \
    ktile<true, true, true, 2, 2>(rA1k0, rA1k1, rB1k1, rA0k0, rB0k0, dA0, dB0, dA1,        \
        pA0, pA1, pB0, pB1, (kt + 2) * 64, (kt + 3) * 64, aX, aY, b0f, b1f, acc);          \
  }                                                                                        \
  ktile<true, false, true, 2, 0>(rA0k0, rA0k1, rB0k1, rA1k0, rB1k0, dA1, dB1, dA0,         \
      pA0, pA1, pB0, pB1, 960, 0, aX, aY, b0f, b1f, acc);                                  \
  ktile<false, false, false, -1, -1>(rA1k0, rA1k1, rB1k1, rA0k0, rB0k0, dA0, dB0, dA1,     \
      pA0, pA1, pB0, pB1, 0, 0, aX, aY, b0f, b1f, acc);

__device__ __forceinline__ void tile_coords(int bid, int& m0, int& n0, int& nt) {
  // 1024 blocks, 8 XCDs, bijective; nt fastest within an XCD for A-panel L2 reuse
  int lin = (bid & 7) * 128 + (bid >> 3);
  int mt = lin >> 2;
  nt = lin & 3;
  m0 = mt * BM;
  n0 = nt * BN;
}

// ---------- prep: convert (2048 blocks) + transpose (512) + query partials (32) ----------
__global__ __launch_bounds__(256) void prep_kernel(
    const float* __restrict__ seq, unsigned short* __restrict__ seqb,
    const float* __restrict__ Wk, const float* __restrict__ Wg,
    unsigned short* __restrict__ WkT, unsigned short* __restrict__ WgT,
    const float* __restrict__ q, const float* __restrict__ Wq,
    float* __restrict__ qp) {
  __shared__ float smem[4160];
  int bid = blockIdx.x, t = threadIdx.x;
  if (bid < 2048) {
    size_t i = ((size_t)bid * 256 + t) * 8;
    const size_t stride = (size_t)2048 * 256 * 8;
    for (; i < (size_t)67108864; i += stride) {
      f32x4 v0 = *(const f32x4*)(seq + i);
      f32x4 v1 = *(const f32x4*)(seq + i + 4);
      ushort8 o;
#pragma unroll
      for (int k = 0; k < 4; ++k) { o[k] = f2bf(v0[k]); o[k + 4] = f2bf(v1[k]); }
      *(ushort8*)(seqb + i) = o;
    }
  } else if (bid < 2560) {
    int b2 = bid - 2048;
    int mat = b2 >> 8;
    int tid = b2 & 255;
    int tr = tid >> 4, tc = tid & 15;
    const float* src = mat ? Wg : Wk;
    unsigned short* dst = mat ? WgT : WkT;
    int r0 = tr * 64, c0 = tc * 64;
    int lr = t >> 6, lc = t & 63;
#pragma unroll
    for (int i = 0; i < 16; ++i) {
      int r = i * 4 + lr;
      smem[r * 65 + lc] = src[(size_t)(r0 + r) * 1024 + c0 + lc];
    }
    __syncthreads();
#pragma unroll
    for (int i = 0; i < 16; ++i) {
      int r = i * 4 + lr;
      dst[(size_t)(c0 + r) * 1024 + r0 + lc] = f2bf(smem[lc * 65 + r]);
    }
  } else {
    // query partials: qp[hc][b][a] = sum_{h in chunk} q[b][h]*Wq[h][a]
    int b3 = bid - 2560;           // 32 blocks
    int ac = b3 & 3, hc = b3 >> 2; // 4 a-chunks x 8 h-chunks
    int h0 = hc * 128;
    for (int i = t; i < 4096; i += 256) {
      int b = i >> 7, hh = i & 127;
      smem[b * 128 + hh] = q[(size_t)b * 1024 + h0 + hh];
    }
    __syncthreads();
    int a = ac * 256 + t;
    float acc[32] = {};
    for (int hh = 0; hh < 128; hh += 4) {
      float w0 = Wq[(size_t)(h0 + hh) * 1024 + a];
      float w1 = Wq[(size_t)(h0 + hh + 1) * 1024 + a];
      float w2 = Wq[(size_t)(h0 + hh + 2) * 1024 + a];
      float w3 = Wq[(size_t)(h0 + hh + 3) * 1024 + a];
#pragma unroll
      for (int b = 0; b < 32; ++b) {
        f32x4 qv = *(const f32x4*)&smem[b * 128 + hh];
        acc[b] += qv[0] * w0 + qv[1] * w1 + qv[2] * w2 + qv[3] * w3;
      }
    }
#pragma unroll
    for (int b = 0; b < 32; ++b) qp[((size_t)(hc * 32 + b)) * 1024 + a] = acc[b];
  }
}

// ---------- GEMM1: align = tanh(seqb@WkT^T + query) -> bf16 ----------
__global__ __launch_bounds__(512, 2) void gemm1_kernel(
    const unsigned short* __restrict__ seqb, const unsigned short* __restrict__ WkT,
    const float* __restrict__ qp, const float* __restrict__ bq,
    const float* __restrict__ bk, unsigned short* __restrict__ alignb) {
  __shared__ unsigned short As0[BM * BK], Bs0[BN * BK], As1[BM * BK], Bs1[BN * BK];
  int m0, n0, nt;
  tile_coords(blockIdx.x, m0, n0, nt);
  GEMM_SETUP_AND_PIPELINE(seqb, WkT)

  // epilogue: fold query reduce (8 partials + bq + bk), tanh, store bf16
  int bidx = m0 >> 11;  // 256-row tile stays in one batch (2048 % 256 == 0)
  float qv[4];
#pragma unroll
  for (int ni = 0; ni < 4; ++ni) {
    int col = n0 + wc * 64 + ni * 16 + (lane & 15);
    float s = bq[col] + bk[col];
#pragma unroll
    for (int hc = 0; hc < 8; ++hc) s += qp[((size_t)(hc * 32 + bidx)) * 1024 + col];
    qv[ni] = s;
  }
#pragma unroll
  for (int mi = 0; mi < 8; ++mi) {
    int row0 = m0 + wr * 128 + mi * 16 + ((lane >> 4) * 4);
#pragma unroll
    for (int ni = 0; ni < 4; ++ni) {
      int col = n0 + wc * 64 + ni * 16 + (lane & 15);
#pragma unroll
      for (int j = 0; j < 4; ++j) {
        float v = fast_tanh(acc[mi][ni][j] + qv[ni]);
        alignb[(size_t)(row0 + j) * 1024 + col] = f2bf(v);
      }
    }
  }
}

// ---------- GEMM2: scores_part[nt,row] = sum_col align*sigmoid(align@Wg+bg)*Ws ----------
__global__ __launch_bounds__(512, 2) void gemm2_kernel(
    const unsigned short* __restrict__ alignb, const unsigned short* __restrict__ WgT,
    const float* __restrict__ bg, const float* __restrict__ Ws,
    float* __restrict__ scores_part) {
  __shared__ unsigned short As0[BM * BK], Bs0[BN * BK], As1[BM * BK], Bs1[BN * BK];
  __shared__ float sred[BM * 4];
  int m0, n0, nt;
  tile_coords(blockIdx.x, m0, n0, nt);
  GEMM_SETUP_AND_PIPELINE(alignb, WgT)

#pragma unroll
  for (int mi = 0; mi < 8; ++mi) {
#pragma unroll
    for (int j = 0; j < 4; ++j) {
      int rloc = wr * 128 + mi * 16 + ((lane >> 4) * 4) + j;
      int row = m0 + rloc;
      float p = 0.f;
#pragma unroll
      for (int ni = 0; ni < 4; ++ni) {
        int col = n0 + wc * 64 + ni * 16 + (lane & 15);
        float gate = fast_sigmoid(acc[mi][ni][j] + bg[col]);
        float al = bf2f(alignb[(size_t)row * 1024 + col]);
        p += al * gate * Ws[col];
      }
      p += __shfl_xor(p, 1);
      p += __shfl_xor(p, 2);
      p += __shfl_xor(p, 4);
      p += __shfl_xor(p, 8);
      if ((lane & 15) == 0) sred[rloc * 4 + wc] = p;
    }
  }
  __syncthreads();
  if (t < 256)
    scores_part[(size_t)nt * 65536 + m0 + t] =
        sred[t * 4] + sred[t * 4 + 1] + sred[t * 4 + 2] + sred[t * 4 + 3];
}

// ---------- softmax over S=2048 per batch; writes weights output ----------
__global__ __launch_bounds__(256) void softmax_kernel(const float* __restrict__ sp,
                                                      float* __restrict__ wout) {
  __shared__ float red[256];
  int b = blockIdx.x, t = threadIdx.x;
  float sc[8];
  float lmax = -1e30f;
#pragma unroll
  for (int i = 0; i < 8; ++i) {
    int s = i * 256 + t;
    float v = 0.f;
#pragma unroll
    for (int n = 0; n < 4; ++n) v += sp[(size_t)n * 65536 + b * 2048 + s];
    sc[i] = v;
    lmax = fmaxf(lmax, v);
  }
  red[t] = lmax;
  __syncthreads();
  for (int off = 128; off > 0; off >>= 1) {
    if (t < off) red[t] = fmaxf(red[t], red[t + off]);
    __syncthreads();
  }
  float mx = red[0];
  __syncthreads();
  float lsum = 0.f;
#pragma unroll
  for (int i = 0; i < 8; ++i) {
    sc[i] = expf(sc[i] - mx);
    lsum += sc[i];
  }
  red[t] = lsum;
  __syncthreads();
  for (int off = 128; off > 0; off >>= 1) {
    if (t < off) red[t] += red[t + off];
    __syncthreads();
  }
  float inv = 1.f / red[0];
#pragma unroll
  for (int i = 0; i < 8; ++i) wout[(size_t)b * 2048 + i * 256 + t] = sc[i] * inv;
}

// ---------- context partials (bf16 seq read, 4 h per thread, 16 s-chunks) ----------
__global__ __launch_bounds__(256) void context_kernel(const unsigned short* __restrict__ seqb,
                                                      const float* __restrict__ wts,
                                                      float* __restrict__ ctx_part) {
  __shared__ float wsh[128];
  int b = blockIdx.x, t = threadIdx.x, s0 = blockIdx.z * 128;
  int h0 = t * 4;
  if (t < 128) wsh[t] = wts[(size_t)b * 2048 + s0 + t];
  __syncthreads();
  float a0 = 0.f, a1 = 0.f, a2 = 0.f, a3 = 0.f;
  const unsigned short* p = seqb + ((size_t)b * 2048 + s0) * 1024 + h0;
#pragma unroll 4
  for (int s = 0; s < 128; ++s) {
    ushortx4 v = *(const ushortx4*)(p + (size_t)s * 1024);
    float w = wsh[s];
    a0 += w * bf2f(v[0]);
    a1 += w * bf2f(v[1]);
    a2 += w * bf2f(v[2]);
    a3 += w * bf2f(v[3]);
  }
  float* dst = ctx_part + (size_t)(blockIdx.z * 32 + b) * 1024 + h0;
  dst[0] = a0; dst[1] = a1; dst[2] = a2; dst[3] = a3;
}

// ---------- pre partials: Wo read ONCE. grid (16 k-chunks of 128, 4 h-chunks) ----------
__global__ __launch_bounds__(256) void pre_kernel(const float* __restrict__ ctx_part,
                                                  const float* __restrict__ q,
                                                  const float* __restrict__ Wo,
                                                  float* __restrict__ pre_part) {
  __shared__ float fin[32 * 128];
  int kc = blockIdx.x, hc = blockIdx.y, t = threadIdx.x;
  int k0 = kc * 128, h0 = hc * 256;
  for (int i = t; i < 4096; i += 256) {
    int b = i >> 7, kk = i & 127, k = k0 + kk;
    float f;
    if (k < 1024) {
      f = 0.f;
#pragma unroll
      for (int s = 0; s < 16; ++s) f += ctx_part[((size_t)(s * 32 + b)) * 1024 + k];
    } else {
      f = q[(size_t)b * 1024 + (k - 1024)];
    }
    fin[b * 128 + kk] = f;
  }
  __syncthreads();
  int h = h0 + t;
  float acc[32] = {};
  for (int kk = 0; kk < 128; kk += 4) {
    float w0 = Wo[(size_t)(k0 + kk) * 1024 + h];
    float w1 = Wo[(size_t)(k0 + kk + 1) * 1024 + h];
    float w2 = Wo[(size_t)(k0 + kk + 2) * 1024 + h];
    float w3 = Wo[(size_t)(k0 + kk + 3) * 1024 + h];
#pragma unroll
    for (int b = 0; b < 32; ++b) {
      f32x4 fv = *(const f32x4*)&fin[b * 128 + kk];
      acc[b] += fv[0] * w0 + fv[1] * w1 + fv[2] * w2 + fv[3] * w3;
    }
  }
#pragma unroll
  for (int b = 0; b < 32; ++b) pre_part[((size_t)(kc * 32 + b)) * 1024 + h] = acc[b];
}

// ---------- final: residual + layernorm ----------
__global__ __launch_bounds__(256) void ln_kernel(const float* __restrict__ pre_part,
                                                 const float* __restrict__ q,
                                                 const float* __restrict__ bo,
                                                 const float* __restrict__ gamma,
                                                 const float* __restrict__ beta,
                                                 float* __restrict__ outF) {
  __shared__ float red[256];
  int b = blockIdx.x, t = threadIdx.x;
  float v[4];
  float lsum = 0.f;
#pragma unroll
  for (int i = 0; i < 4; ++i) {
    int h = i * 256 + t;
    float x = bo[h] + q[(size_t)b * 1024 + h];
#pragma unroll
    for (int kc = 0; kc < 16; ++kc) x += pre_part[((size_t)(kc * 32 + b)) * 1024 + h];
    v[i] = x;
    lsum += x;
  }
  red[t] = lsum;
  __syncthreads();
  for (int off = 128; off > 0; off >>= 1) {
    if (t < off) red[t] += red[t + off];
    __syncthreads();
  }
  float mu = red[0] * (1.f / 1024.f);
  __syncthreads();
  float lv = 0.f;
#pragma unroll
  for (int i = 0; i < 4; ++i) {
    float d = v[i] - mu;
    lv += d * d;
  }
  red[t] = lv;
  __syncthreads();
  for (int off = 128; off > 0; off >>= 1) {
    if (t < off) red[t] += red[t + off];
    __syncthreads();
  }
  float var = red[0] * (1.f / 1024.f);
  float rs = rsqrtf(var + 1e-5f);
#pragma unroll
  for (int i = 0; i < 4; ++i) {
    int h = i * 256 + t;
    outF[(size_t)b * 1024 + h] = (v[i] - mu) * rs * gamma[h] + beta[h];
  }
}

// ---------- host ----------
extern "C" void kernel_launch(void* const* d_in, const int* in_sizes, int n_in,
                              void* d_out, int out_size, void* d_ws, size_t ws_size,
                              hipStream_t stream) {
  const float* seq = (const float*)d_in[0];
  const float* q = (const float*)d_in[1];
  const float* Wk = (const float*)d_in[2];
  const float* bk = (const float*)d_in[3];
  const float* Wq = (const float*)d_in[4];
  const float* bq = (const float*)d_in[5];
  const float* Wg = (const float*)d_in[6];
  const float* bg = (const float*)d_in[7];
  const float* Ws = (const float*)d_in[8];
  // d_in[9] = bs: softmax is shift-invariant, cancels everywhere it appears
  const float* Wo = (const float*)d_in[10];
  const float* bo = (const float*)d_in[11];
  const float* gamma = (const float*)d_in[12];
  const float* beta = (const float*)d_in[13];

  float* outF = (float*)d_out;         // fused [32,1024]
  float* outW = outF + 32 * 1024;      // weights [32,2048]

  char* ws = (char*)d_ws;
  unsigned short* alignb = (unsigned short*)ws;  ws += (size_t)134217728;  // [65536,1024] bf16
  unsigned short* seqb = (unsigned short*)ws;    ws += (size_t)134217728;  // [65536,1024] bf16
  unsigned short* WkT = (unsigned short*)ws;     ws += 2097152;            // [1024,1024] bf16
  unsigned short* WgT = (unsigned short*)ws;     ws += 2097152;
  float* qp = (float*)ws;                        ws += 1048576;            // [8,32,1024]
  float* scores_part = (float*)ws;               ws += 1048576;            // [4,65536]
  float* ctx_part = (float*)ws;                  ws += 2097152;            // [16,32,1024]
  float* pre_part = (float*)ws;                  ws += 2097152;            // [16,32,1024]
  if (ws_size < (size_t)(ws - (char*)d_ws)) return;  // insufficient scratch

  prep_kernel<<<2592, 256, 0, stream>>>(seq, seqb, Wk, Wg, WkT, WgT, q, Wq, qp);
  gemm1_kernel<<<1024, 512, 0, stream>>>(seqb, WkT, qp, bq, bk, alignb);
  gemm2_kernel<<<1024, 512, 0, stream>>>(alignb, WgT, bg, Ws, scores_part);
  softmax_kernel<<<32, 256, 0, stream>>>(scores_part, outW);
  context_kernel<<<dim3(32, 1, 16), 256, 0, stream>>>(seqb, outW, ctx_part);
  pre_kernel<<<dim3(16, 4), 256, 0, stream>>>(ctx_part, q, Wo, pre_part);
  ln_kernel<<<32, 256, 0, stream>>>(pre_part, q, bo, gamma, beta, outF);
}

// Round 10
// 487.945 us; speedup vs baseline: 1.0442x; 1.0369x over previous
//
#include <hip/hip_runtime.h>

typedef __attribute__((ext_vector_type(8))) short bf16x8;
typedef __attribute__((ext_vector_type(8))) unsigned short ushort8;
typedef __attribute__((ext_vector_type(4))) unsigned short ushortx4;
typedef __attribute__((ext_vector_type(4))) float f32x4;

#define BM 256
#define BN 256
#define BK 64

// ---------- helpers ----------
__device__ __forceinline__ unsigned short f2bf(float f) {
  union { float f; unsigned u; } c; c.f = f;
  return (unsigned short)((c.u + 0x7fffu + ((c.u >> 16) & 1u)) >> 16);  // RNE
}
__device__ __forceinline__ float bf2f(unsigned short u) {
  union { unsigned u; float f; } c; c.u = ((unsigned)u) << 16;
  return c.f;
}
__device__ __forceinline__ float fast_tanh(float x) {
  float e = __expf(2.f * x);                       // inf for large x -> rcp->0 -> 1
  return 1.f - 2.f * __builtin_amdgcn_rcpf(e + 1.f);
}
__device__ __forceinline__ float fast_sigmoid(float x) {
  return __builtin_amdgcn_rcpf(1.f + __expf(-x));
}
__device__ __forceinline__ void gload16(const void* g, void* lds) {
  __builtin_amdgcn_global_load_lds(
      (const __attribute__((address_space(1))) unsigned int*)g,
      (__attribute__((address_space(3))) unsigned int*)lds, 16, 0, 0);
}
__device__ __forceinline__ void bar() {
  asm volatile("" ::: "memory");
  __builtin_amdgcn_s_barrier();
  asm volatile("" ::: "memory");
}
__device__ __forceinline__ void sb0() { __builtin_amdgcn_sched_barrier(0); }
template <int N> __device__ __forceinline__ void vlgkm() {
  if constexpr (N == 0) asm volatile("s_waitcnt lgkmcnt(0)" ::: "memory");
  else if constexpr (N == 4) asm volatile("s_waitcnt lgkmcnt(4)" ::: "memory");
  else if constexpr (N == 8) asm volatile("s_waitcnt lgkmcnt(8)" ::: "memory");
}
template <int N> __device__ __forceinline__ void vwait() {
  if constexpr (N < 0) {
  } else if constexpr (N == 2) asm volatile("s_waitcnt vmcnt(2)" ::: "memory");
  else if constexpr (N == 0) asm volatile("s_waitcnt vmcnt(0)" ::: "memory");
}

// 16-MFMA pure cluster: acc[ro+i][n] += a[i] x b[n]
__device__ __forceinline__ void mfma16(const bf16x8 (&a)[4], const bf16x8 (&b)[4], int ro,
                                       f32x4 (&acc)[8][4]) {
  __builtin_amdgcn_s_setprio(1);
#pragma unroll
  for (int i = 0; i < 4; ++i)
#pragma unroll
    for (int n = 0; n < 4; ++n)
      acc[ro + i][n] =
          __builtin_amdgcn_mfma_f32_16x16x32_bf16(a[i], b[n], acc[ro + i][n], 0, 0, 0);
  __builtin_amdgcn_s_setprio(0);
}
__device__ __forceinline__ void mfma16_4(const bf16x8 (&a)[4], const bf16x8 (&b)[4],
                                         f32x4 (&acc)[4][4]) {
#pragma unroll
  for (int i = 0; i < 4; ++i)
#pragma unroll
    for (int n = 0; n < 4; ++n)
      acc[i][n] =
          __builtin_amdgcn_mfma_f32_16x16x32_bf16(a[i], b[n], acc[i][n], 0, 0, 0);
}

// ===== gemm1 (control): r9 software-pipelined 256x256 structure (unchanged) =====
template <bool ST, bool ST4, bool RD4, int W3, int W4>
__device__ __forceinline__ void ktile(
    const char* rAk0, const char* rAk1, const char* rBk1,   // cur-buf read bases
    const char* rAk0n, const char* rBk0n,                   // next-buf (ph4 reads)
    char* dAn, char* dBn,   // stage dests, tile t+1 (next buf), +t*16 applied
    char* dAc,              // stage dest SA0(t+2) (cur buf)
    const unsigned short* pA0, const unsigned short* pA1,
    const unsigned short* pB0, const unsigned short* pB1,
    int kN1, int kN2,
    bf16x8 (&aX)[4], bf16x8 (&aY)[4], bf16x8 (&b0)[4], bf16x8 (&b1)[4],
    f32x4 (&acc)[8][4]) {
  // ---- ph1
  bar();
#pragma unroll
  for (int i = 0; i < 4; ++i) aY[i] = *(const bf16x8*)(rAk0 + 16384 + i * 2048);
  if (ST) { gload16(pB0 + kN1, dBn); gload16(pB1 + kN1, dBn + 8192); }
  vlgkm<4>(); sb0();
  mfma16(aX, b0, 0, acc);
  // ---- ph2
  bar();
#pragma unroll
  for (int i = 0; i < 4; ++i) aX[i] = *(const bf16x8*)(rAk1 + i * 2048);
#pragma unroll
  for (int n = 0; n < 4; ++n)
    b1[n] = *(const bf16x8*)(rBk1 + (n >> 1) * 16384 + (n & 1) * 2048);
  if (ST) { gload16(pB0 + 32768 + kN1, dBn + 16384); gload16(pB1 + 32768 + kN1, dBn + 16384 + 8192); }
  vlgkm<8>(); sb0();
  mfma16(aY, b0, 4, acc);
  // ---- ph3
  bar();
#pragma unroll
  for (int i = 0; i < 4; ++i) aY[i] = *(const bf16x8*)(rAk1 + 16384 + i * 2048);
  if (ST) { gload16(pA0 + 65536 + kN1, dAn + 16384); gload16(pA1 + 65536 + kN1, dAn + 16384 + 8192); }
  vlgkm<4>(); sb0();
  mfma16(aX, b1, 0, acc);
  vwait<W3>();
  // ---- ph4
  bar();
  if (RD4) {
#pragma unroll
    for (int i = 0; i < 4; ++i) aX[i] = *(const bf16x8*)(rAk0n + i * 2048);
#pragma unroll
    for (int n = 0; n < 4; ++n)
      b0[n] = *(const bf16x8*)(rBk0n + (n >> 1) * 16384 + (n & 1) * 2048);
  }
  if (ST4) { gload16(pA0 + kN2, dAc); gload16(pA1 + kN2, dAc + 8192); }
  if (RD4) vlgkm<8>(); else vlgkm<0>();
  sb0();
  mfma16(aY, b1, 4, acc);
  vwait<W4>();
}

#define GEMM_SETUP_AND_PIPELINE(Ag, Bg)                                                    \
  int t = threadIdx.x, lane = t & 63, wave = t >> 6;                                       \
  int wr = wave >> 2, wc = wave & 3;                                                       \
  int sl0 = ((lane >> 4) ^ (lane & 7)) * 16;                                               \
  int sl1 = (((lane >> 4) + 4) ^ (lane & 7)) * 16;                                         \
  int aLane = (wr * 64 + (lane & 15)) * 128;                                               \
  int bLane = (wc * 32 + (lane & 15)) * 128;                                               \
  const char* rA0k0 = (const char*)As0 + aLane + sl0;                                      \
  const char* rA0k1 = (const char*)As0 + aLane + sl1;                                      \
  const char* rA1k0 = (const char*)As1 + aLane + sl0;                                      \
  const char* rA1k1 = (const char*)As1 + aLane + sl1;                                      \
  const char* rB0k0 = (const char*)Bs0 + bLane + sl0;                                      \
  const char* rB0k1 = (const char*)Bs0 + bLane + sl1;                                      \
  const char* rB1k0 = (const char*)Bs1 + bLane + sl0;                                      \
  const char* rB1k1 = (const char*)Bs1 + bLane + sl1;                                      \
  char* dA0 = (char*)As0 + t * 16;                                                         \
  char* dA1 = (char*)As1 + t * 16;                                                         \
  char* dB0 = (char*)Bs0 + t * 16;                                                         \
  char* dB1 = (char*)Bs1 + t * 16;                                                         \
  int l3 = t >> 3;                                                                         \
  int sgE = ((t & 7) ^ (l3 & 7)) * 8;                                                      \
  const unsigned short* pA0 = Ag + (size_t)(m0 + l3) * 1024 + sgE;                         \
  const unsigned short* pA1 = pA0 + (size_t)128 * 1024;                                    \
  int nB0 = ((l3 >> 5) << 6) + (l3 & 31);                                                  \
  const unsigned short* pB0 = Bg + (size_t)(n0 + nB0) * 1024 + sgE;                        \
  const unsigned short* pB1 = pB0 + (size_t)128 * 1024;                                    \
  f32x4 acc[8][4] = {};                                                                    \
  bf16x8 aX[4], aY[4], b0f[4], b1f[4];                                                     \
  gload16(pA0, dA0); gload16(pA1, dA0 + 8192);                                             \
  gload16(pB0, dB0); gload16(pB1, dB0 + 8192);                                             \
  gload16(pB0 + 32768, dB0 + 16384); gload16(pB1 + 32768, dB0 + 16384 + 8192);             \
  gload16(pA0 + 65536, dA0 + 16384); gload16(pA1 + 65536, dA0 + 16384 + 8192);             \
  vwait<2>();                                                                              \
  bar();                                                                                   \
  _Pragma("unroll") for (int i = 0; i < 4; ++i)                                            \
      aX[i] = *(const bf16x8*)(rA0k0 + i * 2048);                                          \
  _Pragma("unroll") for (int n = 0; n < 4; ++n)                                            \
      b0f[n] = *(const bf16x8*)(rB0k0 + (n >> 1) * 16384 + (n & 1) * 2048);                \
  gload16(pA0 + 64, dA1); gload16(pA1 + 64, dA1 + 8192);                                   \
  vwait<2>();                                                                              \
  _Pragma("unroll 1") for (int kt = 0; kt < 14; kt += 2) {                                 \
    ktile<true, true, true, 2, 2>(rA0k0, rA0k1, rB0k1, rA1k0, rB1k0, dA1, dB1, dA0,        \
        pA0, pA1, pB0, pB1, (kt + 1) * 64, (kt + 2) * 64, aX, aY, b0f, b1f, acc);          \
    ktile<true, true, true, 2, 2>(rA1k0, rA1k1, rB1k1, rA0k0, rB0k0, dA0, dB0, dA1,        \
        pA0, pA1, pB0, pB1, (kt + 2) * 64, (kt + 3) * 64, aX, aY, b0f, b1f, acc);          \
  }                                                                                        \
  ktile<true, false, true, 2, 0>(rA0k0, rA0k1, rB0k1, rA1k0, rB1k0, dA1, dB1, dA0,         \
      pA0, pA1, pB0, pB1, 960, 0, aX, aY, b0f, b1f, acc);                                  \
  ktile<false, false, false, -1, -1>(rA1k0, rA1k1, rB1k1, rA0k0, rB0k0, dA0, dB0, dA1,     \
      pA0, pA1, pB0, pB1, 0, 0, aX, aY, b0f, b1f, acc);

__device__ __forceinline__ void tile_coords(int bid, int& m0, int& n0, int& nt) {
  // 1024 blocks, 8 XCDs, bijective; nt fastest within an XCD for A-panel L2 reuse
  int lin = (bid & 7) * 128 + (bid >> 3);
  int mt = lin >> 2;
  nt = lin & 3;
  m0 = mt * BM;
  n0 = nt * BN;
}

// ---------- prep: convert (2048 blocks) + transpose (512) + query partials (32) ----------
__global__ __launch_bounds__(256) void prep_kernel(
    const float* __restrict__ seq, unsigned short* __restrict__ seqb,
    const float* __restrict__ Wk, const float* __restrict__ Wg,
    unsigned short* __restrict__ WkT, unsigned short* __restrict__ WgT,
    const float* __restrict__ q, const float* __restrict__ Wq,
    float* __restrict__ qp) {
  __shared__ float smem[4160];
  int bid = blockIdx.x, t = threadIdx.x;
  if (bid < 2048) {
    size_t i = ((size_t)bid * 256 + t) * 8;
    const size_t stride = (size_t)2048 * 256 * 8;
    for (; i < (size_t)67108864; i += stride) {
      f32x4 v0 = *(const f32x4*)(seq + i);
      f32x4 v1 = *(const f32x4*)(seq + i + 4);
      ushort8 o;
#pragma unroll
      for (int k = 0; k < 4; ++k) { o[k] = f2bf(v0[k]); o[k + 4] = f2bf(v1[k]); }
      *(ushort8*)(seqb + i) = o;
    }
  } else if (bid < 2560) {
    int b2 = bid - 2048;
    int mat = b2 >> 8;
    int tid = b2 & 255;
    int tr = tid >> 4, tc = tid & 15;
    const float* src = mat ? Wg : Wk;
    unsigned short* dst = mat ? WgT : WkT;
    int r0 = tr * 64, c0 = tc * 64;
    int lr = t >> 6, lc = t & 63;
#pragma unroll
    for (int i = 0; i < 16; ++i) {
      int r = i * 4 + lr;
      smem[r * 65 + lc] = src[(size_t)(r0 + r) * 1024 + c0 + lc];
    }
    __syncthreads();
#pragma unroll
    for (int i = 0; i < 16; ++i) {
      int r = i * 4 + lr;
      dst[(size_t)(c0 + r) * 1024 + r0 + lc] = f2bf(smem[lc * 65 + r]);
    }
  } else {
    // query partials: qp[hc][b][a] = sum_{h in chunk} q[b][h]*Wq[h][a]
    int b3 = bid - 2560;           // 32 blocks
    int ac = b3 & 3, hc = b3 >> 2; // 4 a-chunks x 8 h-chunks
    int h0 = hc * 128;
    for (int i = t; i < 4096; i += 256) {
      int b = i >> 7, hh = i & 127;
      smem[b * 128 + hh] = q[(size_t)b * 1024 + h0 + hh];
    }
    __syncthreads();
    int a = ac * 256 + t;
    float acc[32] = {};
    for (int hh = 0; hh < 128; hh += 4) {
      float w0 = Wq[(size_t)(h0 + hh) * 1024 + a];
      float w1 = Wq[(size_t)(h0 + hh + 1) * 1024 + a];
      float w2 = Wq[(size_t)(h0 + hh + 2) * 1024 + a];
      float w3 = Wq[(size_t)(h0 + hh + 3) * 1024 + a];
#pragma unroll
      for (int b = 0; b < 32; ++b) {
        f32x4 qv = *(const f32x4*)&smem[b * 128 + hh];
        acc[b] += qv[0] * w0 + qv[1] * w1 + qv[2] * w2 + qv[3] * w3;
      }
    }
#pragma unroll
    for (int b = 0; b < 32; ++b) qp[((size_t)(hc * 32 + b)) * 1024 + a] = acc[b];
  }
}

// ---------- GEMM1: align = tanh(seqb@WkT^T + query) -> bf16 (r9 structure) ----------
__global__ __launch_bounds__(512, 2) void gemm1_kernel(
    const unsigned short* __restrict__ seqb, const unsigned short* __restrict__ WkT,
    const float* __restrict__ qp, const float* __restrict__ bq,
    const float* __restrict__ bk, unsigned short* __restrict__ alignb) {
  __shared__ unsigned short As0[BM * BK], Bs0[BN * BK], As1[BM * BK], Bs1[BN * BK];
  int m0, n0, nt;
  tile_coords(blockIdx.x, m0, n0, nt);
  GEMM_SETUP_AND_PIPELINE(seqb, WkT)

  // epilogue: fold query reduce (8 partials + bq + bk), tanh, store bf16
  int bidx = m0 >> 11;  // 256-row tile stays in one batch (2048 % 256 == 0)
  float qv[4];
#pragma unroll
  for (int ni = 0; ni < 4; ++ni) {
    int col = n0 + wc * 64 + ni * 16 + (lane & 15);
    float s = bq[col] + bk[col];
#pragma unroll
    for (int hc = 0; hc < 8; ++hc) s += qp[((size_t)(hc * 32 + bidx)) * 1024 + col];
    qv[ni] = s;
  }
#pragma unroll
  for (int mi = 0; mi < 8; ++mi) {
    int row0 = m0 + wr * 128 + mi * 16 + ((lane >> 4) * 4);
#pragma unroll
    for (int ni = 0; ni < 4; ++ni) {
      int col = n0 + wc * 64 + ni * 16 + (lane & 15);
#pragma unroll
      for (int j = 0; j < 4; ++j) {
        float v = fast_tanh(acc[mi][ni][j] + qv[ni]);
        alignb[(size_t)(row0 + j) * 1024 + col] = f2bf(v);
      }
    }
  }
}

// ---------- GEMM2 (A/B test): m97-style 128x128, 4 waves, single-buffer, 2-3 blk/CU ----------
// scores_part[nt,row] = sum_col align*sigmoid(align@Wg+bg)*Ws ; nt in 0..7
__global__ __launch_bounds__(256, 2) void gemm2_kernel(
    const unsigned short* __restrict__ alignb, const unsigned short* __restrict__ WgT,
    const float* __restrict__ bg, const float* __restrict__ Ws,
    float* __restrict__ scores_part) {
  __shared__ unsigned short As[128 * 64];   // 16 KB, single-buffered
  __shared__ unsigned short Bs[128 * 64];   // 16 KB
  __shared__ float sred[128 * 2];
  // 4096 blocks: XCD-bijective, nt (8) fastest within an XCD
  int lin = (blockIdx.x & 7) * 512 + (blockIdx.x >> 3);
  int mt = lin >> 3, nt = lin & 7;
  int m0 = mt * 128, n0 = nt * 128;
  int t = threadIdx.x, lane = t & 63, wave = t >> 6;
  int wr = wave >> 1, wc = wave & 1;   // 2x2 wave grid, each wave 64x64 output
  // LDS read bases: row l = (wr|wc)*64 + i*16 + (lane&15); byte = l*128 + ((s^(l&7))*16)
  int sl0 = ((lane >> 4) ^ (lane & 7)) * 16;
  int sl1 = (((lane >> 4) + 4) ^ (lane & 7)) * 16;
  const char* rAk0 = (const char*)As + (wr * 64 + (lane & 15)) * 128 + sl0;
  const char* rAk1 = (const char*)As + (wr * 64 + (lane & 15)) * 128 + sl1;
  const char* rBk0 = (const char*)Bs + (wc * 64 + (lane & 15)) * 128 + sl0;
  const char* rBk1 = (const char*)Bs + (wc * 64 + (lane & 15)) * 128 + sl1;
  // stage: chunk c = r*256+t (r=0..3); row = c>>3 = r*32+l3; slot s = t&7 (inverse-swz src)
  int l3 = t >> 3;
  int sgE = ((t & 7) ^ (l3 & 7)) * 8;
  const unsigned short* pA = alignb + (size_t)(m0 + l3) * 1024 + sgE;
  const unsigned short* pB = WgT + (size_t)(n0 + l3) * 1024 + sgE;
  char* dA = (char*)As + t * 16;
  char* dB = (char*)Bs + t * 16;
  f32x4 acc[4][4] = {};
#pragma unroll 1
  for (int kt = 0; kt < 16; ++kt) {
    int k0 = kt * 64;
#pragma unroll
    for (int r = 0; r < 4; ++r) {
      gload16(pA + (size_t)(r * 32) * 1024 + k0, dA + r * 4096);
      gload16(pB + (size_t)(r * 32) * 1024 + k0, dB + r * 4096);
    }
    vwait<0>();
    bar();
    {
      bf16x8 a[4], b[4];
#pragma unroll
      for (int i = 0; i < 4; ++i) a[i] = *(const bf16x8*)(rAk0 + i * 2048);
#pragma unroll
      for (int n = 0; n < 4; ++n) b[n] = *(const bf16x8*)(rBk0 + n * 2048);
      mfma16_4(a, b, acc);
#pragma unroll
      for (int i = 0; i < 4; ++i) a[i] = *(const bf16x8*)(rAk1 + i * 2048);
#pragma unroll
      for (int n = 0; n < 4; ++n) b[n] = *(const bf16x8*)(rBk1 + n * 2048);
      mfma16_4(a, b, acc);
    }
    bar();
  }
  // epilogue: gate + weighted row-reduction
#pragma unroll
  for (int mi = 0; mi < 4; ++mi) {
#pragma unroll
    for (int j = 0; j < 4; ++j) {
      int rloc = wr * 64 + mi * 16 + ((lane >> 4) * 4) + j;
      int row = m0 + rloc;
      float p = 0.f;
#pragma unroll
      for (int ni = 0; ni < 4; ++ni) {
        int col = n0 + wc * 64 + ni * 16 + (lane & 15);
        float gate = fast_sigmoid(acc[mi][ni][j] + bg[col]);
        float al = bf2f(alignb[(size_t)row * 1024 + col]);
        p += al * gate * Ws[col];
      }
      p += __shfl_xor(p, 1);
      p += __shfl_xor(p, 2);
      p += __shfl_xor(p, 4);
      p += __shfl_xor(p, 8);
      if ((lane & 15) == 0) sred[rloc * 2 + wc] = p;
    }
  }
  __syncthreads();
  if (t < 128) scores_part[(size_t)nt * 65536 + m0 + t] = sred[t * 2] + sred[t * 2 + 1];
}

// ---------- softmax over S=2048 per batch (8 partials); writes weights output ----------
__global__ __launch_bounds__(256) void softmax_kernel(const float* __restrict__ sp,
                                                      float* __restrict__ wout) {
  __shared__ float red[256];
  int b = blockIdx.x, t = threadIdx.x;
  float sc[8];
  float lmax = -1e30f;
#pragma unroll
  for (int i = 0; i < 8; ++i) {
    int s = i * 256 + t;
    float v = 0.f;
#pragma unroll
    for (int n = 0; n < 8; ++n) v += sp[(size_t)n * 65536 + b * 2048 + s];
    sc[i] = v;
    lmax = fmaxf(lmax, v);
  }
  red[t] = lmax;
  __syncthreads();
  for (int off = 128; off > 0; off >>= 1) {
    if (t < off) red[t] = fmaxf(red[t], red[t + off]);
    __syncthreads();
  }
  float mx = red[0];
  __syncthreads();
  float lsum = 0.f;
#pragma unroll
  for (int i = 0; i < 8; ++i) {
    sc[i] = expf(sc[i] - mx);
    lsum += sc[i];
  }
  red[t] = lsum;
  __syncthreads();
  for (int off = 128; off > 0; off >>= 1) {
    if (t < off) red[t] += red[t + off];
    __syncthreads();
  }
  float inv = 1.f / red[0];
#pragma unroll
  for (int i = 0; i < 8; ++i) wout[(size_t)b * 2048 + i * 256 + t] = sc[i] * inv;
}

// ---------- context partials (bf16 seq read, 4 h per thread, 16 s-chunks) ----------
__global__ __launch_bounds__(256) void context_kernel(const unsigned short* __restrict__ seqb,
                                                      const float* __restrict__ wts,
                                                      float* __restrict__ ctx_part) {
  __shared__ float wsh[128];
  int b = blockIdx.x, t = threadIdx.x, s0 = blockIdx.z * 128;
  int h0 = t * 4;
  if (t < 128) wsh[t] = wts[(size_t)b * 2048 + s0 + t];
  __syncthreads();
  float a0 = 0.f, a1 = 0.f, a2 = 0.f, a3 = 0.f;
  const unsigned short* p = seqb + ((size_t)b * 2048 + s0) * 1024 + h0;
#pragma unroll 4
  for (int s = 0; s < 128; ++s) {
    ushortx4 v = *(const ushortx4*)(p + (size_t)s * 1024);
    float w = wsh[s];
    a0 += w * bf2f(v[0]);
    a1 += w * bf2f(v[1]);
    a2 += w * bf2f(v[2]);
    a3 += w * bf2f(v[3]);
  }
  float* dst = ctx_part + (size_t)(blockIdx.z * 32 + b) * 1024 + h0;
  dst[0] = a0; dst[1] = a1; dst[2] = a2; dst[3] = a3;
}

// ---------- pre partials: Wo read ONCE. grid (16 k-chunks of 128, 4 h-chunks) ----------
__global__ __launch_bounds__(256) void pre_kernel(const float* __restrict__ ctx_part,
                                                  const float* __restrict__ q,
                                                  const float* __restrict__ Wo,
                                                  float* __restrict__ pre_part) {
  __shared__ float fin[32 * 128];
  int kc = blockIdx.x, hc = blockIdx.y, t = threadIdx.x;
  int k0 = kc * 128, h0 = hc * 256;
  for (int i = t; i < 4096; i += 256) {
    int b = i >> 7, kk = i & 127, k = k0 + kk;
    float f;
    if (k < 1024) {
      f = 0.f;
#pragma unroll
      for (int s = 0; s < 16; ++s) f += ctx_part[((size_t)(s * 32 + b)) * 1024 + k];
    } else {
      f = q[(size_t)b * 1024 + (k - 1024)];
    }
    fin[b * 128 + kk] = f;
  }
  __syncthreads();
  int h = h0 + t;
  float acc[32] = {};
  for (int kk = 0; kk < 128; kk += 4) {
    float w0 = Wo[(size_t)(k0 + kk) * 1024 + h];
    float w1 = Wo[(size_t)(k0 + kk + 1) * 1024 + h];
    float w2 = Wo[(size_t)(k0 + kk + 2) * 1024 + h];
    float w3 = Wo[(size_t)(k0 + kk + 3) * 1024 + h];
#pragma unroll
    for (int b = 0; b < 32; ++b) {
      f32x4 fv = *(const f32x4*)&fin[b * 128 + kk];
      acc[b] += fv[0] * w0 + fv[1] * w1 + fv[2] * w2 + fv[3] * w3;
    }
  }
#pragma unroll
  for (int b = 0; b < 32; ++b) pre_part[((size_t)(kc * 32 + b)) * 1024 + h] = acc[b];
}

// ---------- final: residual + layernorm ----------
__global__ __launch_bounds__(256) void ln_kernel(const float* __restrict__ pre_part,
                                                 const float* __restrict__ q,
                                                 const float* __restrict__ bo,
                                                 const float* __restrict__ gamma,
                                                 const float* __restrict__ beta,
                                                 float* __restrict__ outF) {
  __shared__ float red[256];
  int b = blockIdx.x, t = threadIdx.x;
  float v[4];
  float lsum = 0.f;
#pragma unroll
  for (int i = 0; i < 4; ++i) {
    int h = i * 256 + t;
    float x = bo[h] + q[(size_t)b * 1024 + h];
#pragma unroll
    for (int kc = 0; kc < 16; ++kc) x += pre_part[((size_t)(kc * 32 + b)) * 1024 + h];
    v[i] = x;
    lsum += x;
  }
  red[t] = lsum;
  __syncthreads();
  for (int off = 128; off > 0; off >>= 1) {
    if (t < off) red[t] += red[t + off];
    __syncthreads();
  }
  float mu = red[0] * (1.f / 1024.f);
  __syncthreads();
  float lv = 0.f;
#pragma unroll
  for (int i = 0; i < 4; ++i) {
    float d = v[i] - mu;
    lv += d * d;
  }
  red[t] = lv;
  __syncthreads();
  for (int off = 128; off > 0; off >>= 1) {
    if (t < off) red[t] += red[t + off];
    __syncthreads();
  }
  float var = red[0] * (1.f / 1024.f);
  float rs = rsqrtf(var + 1e-5f);
#pragma unroll
  for (int i = 0; i < 4; ++i) {
    int h = i * 256 + t;
    outF[(size_t)b * 1024 + h] = (v[i] - mu) * rs * gamma[h] + beta[h];
  }
}

// ---------- host ----------
extern "C" void kernel_launch(void* const* d_in, const int* in_sizes, int n_in,
                              void* d_out, int out_size, void* d_ws, size_t ws_size,
                              hipStream_t stream) {
  const float* seq = (const float*)d_in[0];
  const float* q = (const float*)d_in[1];
  const float* Wk = (const float*)d_in[2];
  const float* bk = (const float*)d_in[3];
  const float* Wq = (const float*)d_in[4];
  const float* bq = (const float*)d_in[5];
  const float* Wg = (const float*)d_in[6];
  const float* bg = (const float*)d_in[7];
  const float* Ws = (const float*)d_in[8];
  // d_in[9] = bs: softmax is shift-invariant, cancels everywhere it appears
  const float* Wo = (const float*)d_in[10];
  const float* bo = (const float*)d_in[11];
  const float* gamma = (const float*)d_in[12];
  const float* beta = (const float*)d_in[13];

  float* outF = (float*)d_out;         // fused [32,1024]
  float* outW = outF + 32 * 1024;      // weights [32,2048]

  char* ws = (char*)d_ws;
  unsigned short* alignb = (unsigned short*)ws;  ws += (size_t)134217728;  // [65536,1024] bf16
  unsigned short* seqb = (unsigned short*)ws;    ws += (size_t)134217728;  // [65536,1024] bf16
  unsigned short* WkT = (unsigned short*)ws;     ws += 2097152;            // [1024,1024] bf16
  unsigned short* WgT = (unsigned short*)ws;     ws += 2097152;
  float* qp = (float*)ws;                        ws += 1048576;            // [8,32,1024]
  float* scores_part = (float*)ws;               ws += 2097152;            // [8,65536]
  float* ctx_part = (float*)ws;                  ws += 2097152;            // [16,32,1024]
  float* pre_part = (float*)ws;                  ws += 2097152;            // [16,32,1024]
  if (ws_size < (size_t)(ws - (char*)d_ws)) return;  // insufficient scratch

  prep_kernel<<<2592, 256, 0, stream>>>(seq, seqb, Wk, Wg, WkT, WgT, q, Wq, qp);
  gemm1_kernel<<<1024, 512, 0, stream>>>(seqb, WkT, qp, bq, bk, alignb);
  gemm2_kernel<<<4096, 256, 0, stream>>>(alignb, WgT, bg, Ws, scores_part);
  softmax_kernel<<<32, 256, 0, stream>>>(scores_part, outW);
  context_kernel<<<dim3(32, 1, 16), 256, 0, stream>>>(seqb, outW, ctx_part);
  pre_kernel<<<dim3(16, 4), 256, 0, stream>>>(ctx_part, q, Wo, pre_part);
  ln_kernel<<<32, 256, 0, stream>>>(pre_part, q, bo, gamma, beta, outF);
}

// Round 11
// 483.332 us; speedup vs baseline: 1.0542x; 1.0095x over previous
//
#include <hip/hip_runtime.h>

typedef __attribute__((ext_vector_type(8))) short bf16x8;
typedef __attribute__((ext_vector_type(8))) unsigned short ushort8;
typedef __attribute__((ext_vector_type(4))) unsigned short ushortx4;
typedef __attribute__((ext_vector_type(4))) float f32x4;

// ---------- helpers ----------
__device__ __forceinline__ unsigned short f2bf(float f) {
  union { float f; unsigned u; } c; c.f = f;
  return (unsigned short)((c.u + 0x7fffu + ((c.u >> 16) & 1u)) >> 16);  // RNE
}
__device__ __forceinline__ float bf2f(unsigned short u) {
  union { unsigned u; float f; } c; c.u = ((unsigned)u) << 16;
  return c.f;
}
__device__ __forceinline__ float fast_tanh(float x) {
  float e = __expf(2.f * x);                       // inf for large x -> rcp->0 -> 1
  return 1.f - 2.f * __builtin_amdgcn_rcpf(e + 1.f);
}
__device__ __forceinline__ float fast_sigmoid(float x) {
  return __builtin_amdgcn_rcpf(1.f + __expf(-x));
}
__device__ __forceinline__ void gload16(const void* g, void* lds) {
  __builtin_amdgcn_global_load_lds(
      (const __attribute__((address_space(1))) unsigned int*)g,
      (__attribute__((address_space(3))) unsigned int*)lds, 16, 0, 0);
}
__device__ __forceinline__ void bar() {
  asm volatile("" ::: "memory");
  __builtin_amdgcn_s_barrier();
  asm volatile("" ::: "memory");
}
__device__ __forceinline__ void vwait0() {
  asm volatile("s_waitcnt vmcnt(0)" ::: "memory");
}

__device__ __forceinline__ void mfma16_4(const bf16x8 (&a)[4], const bf16x8 (&b)[4],
                                         f32x4 (&acc)[4][4]) {
#pragma unroll
  for (int i = 0; i < 4; ++i)
#pragma unroll
    for (int n = 0; n < 4; ++n)
      acc[i][n] =
          __builtin_amdgcn_mfma_f32_16x16x32_bf16(a[i], b[n], acc[i][n], 0, 0, 0);
}

// ===== shared m97-style 128x128 core: 4 waves, single-buffer, 2 bars/K-tile =====
// LDS layout: row l, byte(l,s) = l*128 + ((s^(l&7))*16); staged linear-dest with
// inverse-swizzled global source (rule #21). Wave (wr,wc) owns 64x64 output.
#define GEMM128_SETUP(Ag, Bg)                                                            \
  int lin = (blockIdx.x & 7) * 512 + (blockIdx.x >> 3);                                  \
  int mt = lin >> 3, nt = lin & 7;                                                       \
  int m0 = mt * 128, n0 = nt * 128;                                                      \
  int t = threadIdx.x, lane = t & 63, wave = t >> 6;                                     \
  int wr = wave >> 1, wc = wave & 1;                                                     \
  int sl0 = ((lane >> 4) ^ (lane & 7)) * 16;                                             \
  int sl1 = (((lane >> 4) + 4) ^ (lane & 7)) * 16;                                       \
  const char* rAk0 = (const char*)As + (wr * 64 + (lane & 15)) * 128 + sl0;              \
  const char* rAk1 = (const char*)As + (wr * 64 + (lane & 15)) * 128 + sl1;              \
  const char* rBk0 = (const char*)Bs + (wc * 64 + (lane & 15)) * 128 + sl0;              \
  const char* rBk1 = (const char*)Bs + (wc * 64 + (lane & 15)) * 128 + sl1;              \
  int l3 = t >> 3;                                                                       \
  int sgE = ((t & 7) ^ (l3 & 7)) * 8;                                                    \
  const unsigned short* pA = Ag + (size_t)(m0 + l3) * 1024 + sgE;                        \
  const unsigned short* pB = Bg + (size_t)(n0 + l3) * 1024 + sgE;                        \
  char* dA = (char*)As + t * 16;                                                         \
  char* dB = (char*)Bs + t * 16;                                                         \
  f32x4 acc[4][4] = {};                                                                  \
  _Pragma("unroll 1") for (int kt = 0; kt < 16; ++kt) {                                  \
    int k0 = kt * 64;                                                                    \
    _Pragma("unroll") for (int r = 0; r < 4; ++r) {                                      \
      gload16(pA + (size_t)(r * 32) * 1024 + k0, dA + r * 4096);                         \
      gload16(pB + (size_t)(r * 32) * 1024 + k0, dB + r * 4096);                         \
    }                                                                                    \
    vwait0();                                                                            \
    bar();                                                                               \
    {                                                                                    \
      bf16x8 a[4], b[4];                                                                 \
      _Pragma("unroll") for (int i = 0; i < 4; ++i)                                      \
          a[i] = *(const bf16x8*)(rAk0 + i * 2048);                                      \
      _Pragma("unroll") for (int n = 0; n < 4; ++n)                                      \
          b[n] = *(const bf16x8*)(rBk0 + n * 2048);                                      \
      mfma16_4(a, b, acc);                                                               \
      _Pragma("unroll") for (int i = 0; i < 4; ++i)                                      \
          a[i] = *(const bf16x8*)(rAk1 + i * 2048);                                      \
      _Pragma("unroll") for (int n = 0; n < 4; ++n)                                      \
          b[n] = *(const bf16x8*)(rBk1 + n * 2048);                                      \
      mfma16_4(a, b, acc);                                                               \
    }                                                                                    \
    bar();                                                                               \
  }

// ---------- prep: convert (2048 blocks) + transpose (512) + query partials (32) ----------
__global__ __launch_bounds__(256) void prep_kernel(
    const float* __restrict__ seq, unsigned short* __restrict__ seqb,
    const float* __restrict__ Wk, const float* __restrict__ Wg,
    unsigned short* __restrict__ WkT, unsigned short* __restrict__ WgT,
    const float* __restrict__ q, const float* __restrict__ Wq,
    float* __restrict__ qp) {
  __shared__ float smem[4160];
  int bid = blockIdx.x, t = threadIdx.x;
  if (bid < 2048) {
    size_t i = ((size_t)bid * 256 + t) * 8;
    const size_t stride = (size_t)2048 * 256 * 8;
    for (; i < (size_t)67108864; i += stride) {
      f32x4 v0 = *(const f32x4*)(seq + i);
      f32x4 v1 = *(const f32x4*)(seq + i + 4);
      ushort8 o;
#pragma unroll
      for (int k = 0; k < 4; ++k) { o[k] = f2bf(v0[k]); o[k + 4] = f2bf(v1[k]); }
      *(ushort8*)(seqb + i) = o;
    }
  } else if (bid < 2560) {
    int b2 = bid - 2048;
    int mat = b2 >> 8;
    int tid = b2 & 255;
    int tr = tid >> 4, tc = tid & 15;
    const float* src = mat ? Wg : Wk;
    unsigned short* dst = mat ? WgT : WkT;
    int r0 = tr * 64, c0 = tc * 64;
    int lr = t >> 6, lc = t & 63;
#pragma unroll
    for (int i = 0; i < 16; ++i) {
      int r = i * 4 + lr;
      smem[r * 65 + lc] = src[(size_t)(r0 + r) * 1024 + c0 + lc];
    }
    __syncthreads();
#pragma unroll
    for (int i = 0; i < 16; ++i) {
      int r = i * 4 + lr;
      dst[(size_t)(c0 + r) * 1024 + r0 + lc] = f2bf(smem[lc * 65 + r]);
    }
  } else {
    // query partials: qp[hc][b][a] = sum_{h in chunk} q[b][h]*Wq[h][a]
    int b3 = bid - 2560;           // 32 blocks
    int ac = b3 & 3, hc = b3 >> 2; // 4 a-chunks x 8 h-chunks
    int h0 = hc * 128;
    for (int i = t; i < 4096; i += 256) {
      int b = i >> 7, hh = i & 127;
      smem[b * 128 + hh] = q[(size_t)b * 1024 + h0 + hh];
    }
    __syncthreads();
    int a = ac * 256 + t;
    float acc[32] = {};
    for (int hh = 0; hh < 128; hh += 4) {
      float w0 = Wq[(size_t)(h0 + hh) * 1024 + a];
      float w1 = Wq[(size_t)(h0 + hh + 1) * 1024 + a];
      float w2 = Wq[(size_t)(h0 + hh + 2) * 1024 + a];
      float w3 = Wq[(size_t)(h0 + hh + 3) * 1024 + a];
#pragma unroll
      for (int b = 0; b < 32; ++b) {
        f32x4 qv = *(const f32x4*)&smem[b * 128 + hh];
        acc[b] += qv[0] * w0 + qv[1] * w1 + qv[2] * w2 + qv[3] * w3;
      }
    }
#pragma unroll
    for (int b = 0; b < 32; ++b) qp[((size_t)(hc * 32 + b)) * 1024 + a] = acc[b];
  }
}

// ---------- GEMM1 (128^2): align = tanh(seqb@WkT^T + query) -> bf16 ----------
__global__ __launch_bounds__(256, 2) void gemm1_kernel(
    const unsigned short* __restrict__ seqb, const unsigned short* __restrict__ WkT,
    const float* __restrict__ qp, const float* __restrict__ bq,
    const float* __restrict__ bk, unsigned short* __restrict__ alignb) {
  __shared__ unsigned short As[128 * 64];
  __shared__ unsigned short Bs[128 * 64];
  GEMM128_SETUP(seqb, WkT)

  // epilogue: fold query reduce (8 partials + bq + bk), tanh, store bf16
  int bidx = m0 >> 11;  // 128-row tile stays in one batch (2048 % 128 == 0)
  float qv[4];
#pragma unroll
  for (int ni = 0; ni < 4; ++ni) {
    int col = n0 + wc * 64 + ni * 16 + (lane & 15);
    float s = bq[col] + bk[col];
#pragma unroll
    for (int hc = 0; hc < 8; ++hc) s += qp[((size_t)(hc * 32 + bidx)) * 1024 + col];
    qv[ni] = s;
  }
#pragma unroll
  for (int mi = 0; mi < 4; ++mi) {
    int row0 = m0 + wr * 64 + mi * 16 + ((lane >> 4) * 4);
#pragma unroll
    for (int ni = 0; ni < 4; ++ni) {
      int col = n0 + wc * 64 + ni * 16 + (lane & 15);
#pragma unroll
      for (int j = 0; j < 4; ++j) {
        float v = fast_tanh(acc[mi][ni][j] + qv[ni]);
        alignb[(size_t)(row0 + j) * 1024 + col] = f2bf(v);
      }
    }
  }
}

// ---------- GEMM2 (128^2): scores_part[nt,row] = sum_col align*sigmoid(align@Wg+bg)*Ws ----------
__global__ __launch_bounds__(256, 2) void gemm2_kernel(
    const unsigned short* __restrict__ alignb, const unsigned short* __restrict__ WgT,
    const float* __restrict__ bg, const float* __restrict__ Ws,
    float* __restrict__ scores_part) {
  __shared__ unsigned short As[128 * 64];
  __shared__ unsigned short Bs[128 * 64];
  __shared__ float sred[128 * 2];
  GEMM128_SETUP(alignb, WgT)

  // epilogue: gate + weighted row-reduction
#pragma unroll
  for (int mi = 0; mi < 4; ++mi) {
#pragma unroll
    for (int j = 0; j < 4; ++j) {
      int rloc = wr * 64 + mi * 16 + ((lane >> 4) * 4) + j;
      int row = m0 + rloc;
      float p = 0.f;
#pragma unroll
      for (int ni = 0; ni < 4; ++ni) {
        int col = n0 + wc * 64 + ni * 16 + (lane & 15);
        float gate = fast_sigmoid(acc[mi][ni][j] + bg[col]);
        float al = bf2f(alignb[(size_t)row * 1024 + col]);
        p += al * gate * Ws[col];
      }
      p += __shfl_xor(p, 1);
      p += __shfl_xor(p, 2);
      p += __shfl_xor(p, 4);
      p += __shfl_xor(p, 8);
      if ((lane & 15) == 0) sred[rloc * 2 + wc] = p;
    }
  }
  __syncthreads();
  if (t < 128) scores_part[(size_t)nt * 65536 + m0 + t] = sred[t * 2] + sred[t * 2 + 1];
}

// ---------- softmax over S=2048 per batch (8 partials); writes weights output ----------
__global__ __launch_bounds__(256) void softmax_kernel(const float* __restrict__ sp,
                                                      float* __restrict__ wout) {
  __shared__ float red[256];
  int b = blockIdx.x, t = threadIdx.x;
  float sc[8];
  float lmax = -1e30f;
#pragma unroll
  for (int i = 0; i < 8; ++i) {
    int s = i * 256 + t;
    float v = 0.f;
#pragma unroll
    for (int n = 0; n < 8; ++n) v += sp[(size_t)n * 65536 + b * 2048 + s];
    sc[i] = v;
    lmax = fmaxf(lmax, v);
  }
  red[t] = lmax;
  __syncthreads();
  for (int off = 128; off > 0; off >>= 1) {
    if (t < off) red[t] = fmaxf(red[t], red[t + off]);
    __syncthreads();
  }
  float mx = red[0];
  __syncthreads();
  float lsum = 0.f;
#pragma unroll
  for (int i = 0; i < 8; ++i) {
    sc[i] = expf(sc[i] - mx);
    lsum += sc[i];
  }
  red[t] = lsum;
  __syncthreads();
  for (int off = 128; off > 0; off >>= 1) {
    if (t < off) red[t] += red[t + off];
    __syncthreads();
  }
  float inv = 1.f / red[0];
#pragma unroll
  for (int i = 0; i < 8; ++i) wout[(size_t)b * 2048 + i * 256 + t] = sc[i] * inv;
}

// ---------- context partials (bf16 seq read, 4 h per thread, 16 s-chunks) ----------
__global__ __launch_bounds__(256) void context_kernel(const unsigned short* __restrict__ seqb,
                                                      const float* __restrict__ wts,
                                                      float* __restrict__ ctx_part) {
  __shared__ float wsh[128];
  int b = blockIdx.x, t = threadIdx.x, s0 = blockIdx.z * 128;
  int h0 = t * 4;
  if (t < 128) wsh[t] = wts[(size_t)b * 2048 + s0 + t];
  __syncthreads();
  float a0 = 0.f, a1 = 0.f, a2 = 0.f, a3 = 0.f;
  const unsigned short* p = seqb + ((size_t)b * 2048 + s0) * 1024 + h0;
#pragma unroll 4
  for (int s = 0; s < 128; ++s) {
    ushortx4 v = *(const ushortx4*)(p + (size_t)s * 1024);
    float w = wsh[s];
    a0 += w * bf2f(v[0]);
    a1 += w * bf2f(v[1]);
    a2 += w * bf2f(v[2]);
    a3 += w * bf2f(v[3]);
  }
  float* dst = ctx_part + (size_t)(blockIdx.z * 32 + b) * 1024 + h0;
  dst[0] = a0; dst[1] = a1; dst[2] = a2; dst[3] = a3;
}

// ---------- pre partials: Wo read ONCE. grid (16 k-chunks of 128, 4 h-chunks) ----------
__global__ __launch_bounds__(256) void pre_kernel(const float* __restrict__ ctx_part,
                                                  const float* __restrict__ q,
                                                  const float* __restrict__ Wo,
                                                  float* __restrict__ pre_part) {
  __shared__ float fin[32 * 128];
  int kc = blockIdx.x, hc = blockIdx.y, t = threadIdx.x;
  int k0 = kc * 128, h0 = hc * 256;
  for (int i = t; i < 4096; i += 256) {
    int b = i >> 7, kk = i & 127, k = k0 + kk;
    float f;
    if (k < 1024) {
      f = 0.f;
#pragma unroll
      for (int s = 0; s < 16; ++s) f += ctx_part[((size_t)(s * 32 + b)) * 1024 + k];
    } else {
      f = q[(size_t)b * 1024 + (k - 1024)];
    }
    fin[b * 128 + kk] = f;
  }
  __syncthreads();
  int h = h0 + t;
  float acc[32] = {};
  for (int kk = 0; kk < 128; kk += 4) {
    float w0 = Wo[(size_t)(k0 + kk) * 1024 + h];
    float w1 = Wo[(size_t)(k0 + kk + 1) * 1024 + h];
    float w2 = Wo[(size_t)(k0 + kk + 2) * 1024 + h];
    float w3 = Wo[(size_t)(k0 + kk + 3) * 1024 + h];
#pragma unroll
    for (int b = 0; b < 32; ++b) {
      f32x4 fv = *(const f32x4*)&fin[b * 128 + kk];
      acc[b] += fv[0] * w0 + fv[1] * w1 + fv[2] * w2 + fv[3] * w3;
    }
  }
#pragma unroll
  for (int b = 0; b < 32; ++b) pre_part[((size_t)(kc * 32 + b)) * 1024 + h] = acc[b];
}

// ---------- final: residual + layernorm ----------
__global__ __launch_bounds__(256) void ln_kernel(const float* __restrict__ pre_part,
                                                 const float* __restrict__ q,
                                                 const float* __restrict__ bo,
                                                 const float* __restrict__ gamma,
                                                 const float* __restrict__ beta,
                                                 float* __restrict__ outF) {
  __shared__ float red[256];
  int b = blockIdx.x, t = threadIdx.x;
  float v[4];
  float lsum = 0.f;
#pragma unroll
  for (int i = 0; i < 4; ++i) {
    int h = i * 256 + t;
    float x = bo[h] + q[(size_t)b * 1024 + h];
#pragma unroll
    for (int kc = 0; kc < 16; ++kc) x += pre_part[((size_t)(kc * 32 + b)) * 1024 + h];
    v[i] = x;
    lsum += x;
  }
  red[t] = lsum;
  __syncthreads();
  for (int off = 128; off > 0; off >>= 1) {
    if (t < off) red[t] += red[t + off];
    __syncthreads();
  }
  float mu = red[0] * (1.f / 1024.f);
  __syncthreads();
  float lv = 0.f;
#pragma unroll
  for (int i = 0; i < 4; ++i) {
    float d = v[i] - mu;
    lv += d * d;
  }
  red[t] = lv;
  __syncthreads();
  for (int off = 128; off > 0; off >>= 1) {
    if (t < off) red[t] += red[t + off];
    __syncthreads();
  }
  float var = red[0] * (1.f / 1024.f);
  float rs = rsqrtf(var + 1e-5f);
#pragma unroll
  for (int i = 0; i < 4; ++i) {
    int h = i * 256 + t;
    outF[(size_t)b * 1024 + h] = (v[i] - mu) * rs * gamma[h] + beta[h];
  }
}

// ---------- host ----------
extern "C" void kernel_launch(void* const* d_in, const int* in_sizes, int n_in,
                              void* d_out, int out_size, void* d_ws, size_t ws_size,
                              hipStream_t stream) {
  const float* seq = (const float*)d_in[0];
  const float* q = (const float*)d_in[1];
  const float* Wk = (const float*)d_in[2];
  const float* bk = (const float*)d_in[3];
  const float* Wq = (const float*)d_in[4];
  const float* bq = (const float*)d_in[5];
  const float* Wg = (const float*)d_in[6];
  const float* bg = (const float*)d_in[7];
  const float* Ws = (const float*)d_in[8];
  // d_in[9] = bs: softmax is shift-invariant, cancels everywhere it appears
  const float* Wo = (const float*)d_in[10];
  const float* bo = (const float*)d_in[11];
  const float* gamma = (const float*)d_in[12];
  const float* beta = (const float*)d_in[13];

  float* outF = (float*)d_out;         // fused [32,1024]
  float* outW = outF + 32 * 1024;      // weights [32,2048]

  char* ws = (char*)d_ws;
  unsigned short* alignb = (unsigned short*)ws;  ws += (size_t)134217728;  // [65536,1024] bf16
  unsigned short* seqb = (unsigned short*)ws;    ws += (size_t)134217728;  // [65536,1024] bf16
  unsigned short* WkT = (unsigned short*)ws;     ws += 2097152;            // [1024,1024] bf16
  unsigned short* WgT = (unsigned short*)ws;     ws += 2097152;
  float* qp = (float*)ws;                        ws += 1048576;            // [8,32,1024]
  float* scores_part = (float*)ws;               ws += 2097152;            // [8,65536]
  float* ctx_part = (float*)ws;                  ws += 2097152;            // [16,32,1024]
  float* pre_part = (float*)ws;                  ws += 2097152;            // [16,32,1024]
  if (ws_size < (size_t)(ws - (char*)d_ws)) return;  // insufficient scratch

  prep_kernel<<<2592, 256, 0, stream>>>(seq, seqb, Wk, Wg, WkT, WgT, q, Wq, qp);
  gemm1_kernel<<<4096, 256, 0, stream>>>(seqb, WkT, qp, bq, bk, alignb);
  gemm2_kernel<<<4096, 256, 0, stream>>>(alignb, WgT, bg, Ws, scores_part);
  softmax_kernel<<<32, 256, 0, stream>>>(scores_part, outW);
  context_kernel<<<dim3(32, 1, 16), 256, 0, stream>>>(seqb, outW, ctx_part);
  pre_kernel<<<dim3(16, 4), 256, 0, stream>>>(ctx_part, q, Wo, pre_part);
  ln_kernel<<<32, 256, 0, stream>>>(pre_part, q, bo, gamma, beta, outF);
}